// Round 7
// baseline (2295.398 us; speedup 1.0000x reference)
//
#include <hip/hip_runtime.h>
#include <cfloat>

// PointNet / DGCNN: B=64, N=1024, F=5, W=128, K=2, D2=768
// R7: knn128 full-row blocks: grid 512 (=2/CU exact), A-tile (128i x 128k,
//     64 KB swizzled LDS) staged ONCE, B streamed in 32-k chunks (16 KB),
//     running top-2 in registers across all 8 j-tiles, single end merge,
//     idx written directly (pn_knn_merge + cand eliminated). 80 KB LDS
//     = exactly 2 blocks/CU. FMA density ~90% vs R5's 62%. k-order and
//     selection order unchanged -> bit-identical picks.

__device__ __forceinline__ void top2_update(float& d1, int& j1, float& d2, int& j2,
                                            float dd, int j) {
  if (dd < d1 || (dd == d1 && j < j1)) { d2 = d1; j2 = j1; d1 = dd; j1 = j; }
  else if (dd < d2 || (dd == d2 && j < j2)) { d2 = dd; j2 = j; }
}

__device__ __forceinline__ void top2_merge_xor(float& d1, int& j1, float& d2, int& j2, int m) {
  float od1 = __shfl_xor(d1, m, 64); int oj1 = __shfl_xor(j1, m, 64);
  float od2 = __shfl_xor(d2, m, 64); int oj2 = __shfl_xor(j2, m, 64);
  bool aw = (d1 < od1) || (d1 == od1 && j1 < oj1);
  float h2d = aw ? d2 : od2;  int h2j = aw ? j2 : oj2;
  float lmd = aw ? od1 : d1;  int lmj = aw ? oj1 : j1;
  float nd1 = aw ? d1 : od1;  int nj1 = aw ? j1 : oj1;
  bool bw = (h2d < lmd) || (h2d == lmd && h2j < lmj);
  d1 = nd1; j1 = nj1;
  d2 = bw ? h2d : lmd; j2 = bw ? h2j : lmj;
}

__device__ __forceinline__ void top2_reduce_wave(float& d1, int& j1, float& d2, int& j2) {
  #pragma unroll
  for (int m = 1; m < 64; m <<= 1) top2_merge_xor(d1, j1, d2, j2, m);
}

// ---------------- KNN on 5-dim x ----------------
__global__ __launch_bounds__(256) void pn_knn5(const float* __restrict__ x,
                                               int* __restrict__ idx) {
  __shared__ float xs[5120];
  int t = threadIdx.x;
  int b = blockIdx.x >> 8;
  int r0 = (blockIdx.x & 255) * 4;
  const float4* xb4 = (const float4*)(x + (size_t)b * 5120);
  #pragma unroll
  for (int s = 0; s < 5; ++s) ((float4*)xs)[t + 256 * s] = xb4[t + 256 * s];
  __syncthreads();
  int wv = t >> 6, lane = t & 63;
  int i = r0 + wv;
  float x0 = xs[i*5+0], x1 = xs[i*5+1], x2 = xs[i*5+2], x3 = xs[i*5+3], x4 = xs[i*5+4];
  float d1 = FLT_MAX, d2 = FLT_MAX; int j1 = 0x7fffffff, j2 = 0x7fffffff;
  for (int tS = 0; tS < 16; ++tS) {
    int j = tS * 64 + lane;
    const float* xj = &xs[j * 5];
    float f0 = xj[0] - x0, f1 = xj[1] - x1, f2 = xj[2] - x2, f3 = xj[3] - x3, f4 = xj[4] - x4;
    float dd = f0*f0 + f1*f1 + f2*f2 + f3*f3 + f4*f4;
    top2_update(d1, j1, d2, j2, dd, j);
  }
  top2_reduce_wave(d1, j1, d2, j2);
  if (lane == 0) {
    int r = b * 1024 + i;
    idx[r*2+0] = j1; idx[r*2+1] = j2;
  }
}

// ---------------- conv1 layer1: x rows staged in LDS ----------------
__global__ __launch_bounds__(256) void pn_conv1_l1(const float* __restrict__ x,
                                                   const int* __restrict__ idx,
                                                   const float* __restrict__ w1,
                                                   const float* __restrict__ b1,
                                                   float* __restrict__ h1) {
  __shared__ float Ws[1280];
  __shared__ float Bs[128];
  __shared__ float xs[8][10];
  __shared__ int   js[8];
  int t = threadIdx.x;
  int r0 = blockIdx.x * 8;
  for (int s = t; s < 1280; s += 256) Ws[s] = w1[s];
  if (t < 128) Bs[t] = b1[t];
  if (t < 8) {
    int r = r0 + t; int i = r >> 1, k = r & 1;
    js[t] = idx[i*2 + k];
  }
  __syncthreads();
  if (t < 80) {
    int row = t / 10, f = t % 10;
    int r = r0 + row; int i = r >> 1;
    if (f < 5) xs[row][f] = x[(size_t)i * 5 + f];
    else {
      int jrow = ((i >> 10) << 10) + js[row];
      xs[row][f] = x[(size_t)jrow * 5 + (f - 5)];
    }
  }
  __syncthreads();
  int c = t & 127, rr = t >> 7;
  #pragma unroll
  for (int s = 0; s < 4; ++s) {
    int row = s * 2 + rr;
    float acc = Bs[c];
    #pragma unroll
    for (int f = 0; f < 5; ++f) {
      float a = xs[row][f];
      float d = xs[row][5+f] - a;
      acc = fmaf(a, Ws[f*128 + c], acc);
      acc = fmaf(d, Ws[(5+f)*128 + c], acc);
    }
    h1[(size_t)(r0 + row) * 128 + c] = fmaxf(acc, 0.0f);
  }
}

// ---------------- GEMM core: A[128 rows] @ W[128,128] ----------------
template<bool RELU, bool PAIRMAX>
__device__ __forceinline__ void gemm128_core(int bid, const float* __restrict__ A,
                                             const float* __restrict__ W,
                                             const float* __restrict__ bias,
                                             float* __restrict__ out) {
  __shared__ __align__(16) float As[4096];
  __shared__ __align__(16) float Wsb[32][132];
  int t = threadIdx.x;
  int rg = t >> 4;
  int cg = t & 15;
  float acc[8][8];
  #pragma unroll
  for (int a = 0; a < 8; ++a)
    #pragma unroll
    for (int b = 0; b < 8; ++b) acc[a][b] = 0.f;
  size_t r0 = (size_t)bid * 128;
  int ra = t >> 1, hf = t & 1;
  int wb = t >> 3, cp = t & 7;
  for (int w0 = 0; w0 < 128; w0 += 32) {
    const float* asrc = A + (r0 + ra) * 128 + w0 + hf * 16;
    #pragma unroll
    for (int q = 0; q < 4; ++q) {
      float4 v = ((const float4*)asrc)[q];
      int base = ((hf << 4) + (q << 2)) * 128 +
                 ((((ra >> 3) ^ ((hf << 2) + q)) << 3) | (ra & 7));
      As[base] = v.x; As[base+128] = v.y; As[base+256] = v.z; As[base+384] = v.w;
    }
    const float* wsrc = W + (size_t)(w0 + wb) * 128 + cp * 16;
    #pragma unroll
    for (int q = 0; q < 4; ++q)
      *(float4*)&Wsb[wb][cp*16 + q*4] = ((const float4*)wsrc)[q];
    __syncthreads();
    #pragma unroll
    for (int k4 = 0; k4 < 8; ++k4) {
      const float* pa = &As[(k4 << 9) + ((rg ^ k4) << 3)];
      #pragma unroll
      for (int kk = 0; kk < 4; ++kk) {
        int w = (k4 << 2) + kk;
        float4 a0 = *(const float4*)(pa + (kk << 7));
        float4 a1 = *(const float4*)(pa + (kk << 7) + 4);
        float4 wv0 = *(const float4*)&Wsb[w][cg*4];
        float4 wv1 = *(const float4*)&Wsb[w][64 + cg*4];
        float av[8] = {a0.x,a0.y,a0.z,a0.w,a1.x,a1.y,a1.z,a1.w};
        float wv[8] = {wv0.x,wv0.y,wv0.z,wv0.w,wv1.x,wv1.y,wv1.z,wv1.w};
        #pragma unroll
        for (int ri = 0; ri < 8; ++ri)
          #pragma unroll
          for (int ci = 0; ci < 8; ++ci)
            acc[ri][ci] = fmaf(av[ri], wv[ci], acc[ri][ci]);
      }
    }
    __syncthreads();
  }
  float blo[4], bhi[4];
  #pragma unroll
  for (int ci = 0; ci < 4; ++ci) {
    blo[ci] = bias ? bias[cg*4 + ci] : 0.f;
    bhi[ci] = bias ? bias[64 + cg*4 + ci] : 0.f;
  }
  if (PAIRMAX) {
    #pragma unroll
    for (int ri = 0; ri < 8; ri += 2) {
      size_t orow = (r0 + rg*8 + ri) >> 1;
      float lo[4], hi[4];
      #pragma unroll
      for (int ci = 0; ci < 4; ++ci) {
        float v0 = acc[ri][ci]   + blo[ci];
        float v1 = acc[ri+1][ci] + blo[ci];
        lo[ci] = fmaxf(fmaxf(v0, v1), 0.f);
        float w0v = acc[ri][ci+4]   + bhi[ci];
        float w1v = acc[ri+1][ci+4] + bhi[ci];
        hi[ci] = fmaxf(fmaxf(w0v, w1v), 0.f);
      }
      *(float4*)&out[orow*128 + cg*4]      = *(float4*)lo;
      *(float4*)&out[orow*128 + 64 + cg*4] = *(float4*)hi;
    }
  } else {
    #pragma unroll
    for (int ri = 0; ri < 8; ++ri) {
      size_t row = r0 + rg*8 + ri;
      float lo[4], hi[4];
      #pragma unroll
      for (int ci = 0; ci < 4; ++ci) {
        float v0 = acc[ri][ci]   + blo[ci];
        float v1 = acc[ri][ci+4] + bhi[ci];
        lo[ci] = RELU ? fmaxf(v0, 0.f) : v0;
        hi[ci] = RELU ? fmaxf(v1, 0.f) : v1;
      }
      *(float4*)&out[row*128 + cg*4]      = *(float4*)lo;
      *(float4*)&out[row*128 + 64 + cg*4] = *(float4*)hi;
    }
  }
}

__global__ __launch_bounds__(256) void pn_gemm128_bias(const float* __restrict__ A,
                                                       const float* __restrict__ W,
                                                       const float* __restrict__ bias,
                                                       float* __restrict__ out) {
  gemm128_core<true, true>(blockIdx.x, A, W, bias, out);
}

__global__ __launch_bounds__(256) void pn_gemm128_uv(const float* __restrict__ A,
                                                     const float* __restrict__ Wb,
                                                     float* __restrict__ U,
                                                     float* __restrict__ V) {
  int which = blockIdx.x >> 9;
  gemm128_core<false, false>(blockIdx.x & 511, A, Wb + (which << 14), nullptr,
                             which ? V : U);
}

// ---------------- row squared norms ----------------
__global__ __launch_bounds__(256) void pn_sqnorm(const float* __restrict__ y,
                                                 float* __restrict__ sq) {
  int r = blockIdx.x * 256 + threadIdx.x;
  const float4* p = (const float4*)(y + (size_t)r * 128);
  float s = 0.f;
  #pragma unroll
  for (int q = 0; q < 32; ++q) {
    float4 v = p[q];
    s += v.x*v.x + v.y*v.y + v.z*v.z + v.w*v.w;
  }
  sq[r] = s;
}

// ---------------- KNN-128: one block per 128-i tile, all 1024 j ----------------
// grid = 64 ev x 8 itiles = 512 blocks (2/CU). A staged once (64 KB swizzled),
// B streamed in 32-k chunks (16 KB). Running top-2 in regs, single end merge.
__global__ __launch_bounds__(256) void pn_knn128(const float* __restrict__ Y,
                                                 const float* __restrict__ sqn,
                                                 int* __restrict__ idx) {
  __shared__ __align__(16) float As[16384];  // [128k][128i] swizzled (64 KB)
  __shared__ __align__(16) float Bs[4096];   // [32k][128j]  swizzled (16 KB)
  int t = threadIdx.x;
  int rg = t >> 4, cg = t & 15;
  int b  = blockIdx.x >> 3;
  int it = blockIdx.x & 7;
  int i0 = it * 128;
  const float* Yb  = Y   + (size_t)b * 131072;
  const float* sqb = sqn + b * 1024;

  int kq = t & 7, rowA = t >> 3;    // rowA in [0,32)

  // ---- stage A tile once ----
  #pragma unroll
  for (int cc = 0; cc < 4; ++cc)
    #pragma unroll
    for (int q = 0; q < 4; ++q) {
      float4 v = *(const float4*)&Yb[(size_t)(i0 + rowA + 32*q) * 128 + cc*32 + kq*4];
      int kg = cc*8 + kq;
      int row = rowA + 32*q;
      int base = (kg << 9) + ((((row >> 3) ^ kq) << 3) | (row & 7));
      As[base] = v.x; As[base+128] = v.y; As[base+256] = v.z; As[base+384] = v.w;
    }
  // ---- stage B chunk 0 (j-tile 0, k 0..31) ----
  float4 pB[4];
  #pragma unroll
  for (int q = 0; q < 4; ++q)
    pB[q] = *(const float4*)&Yb[(size_t)(rowA + 32*q) * 128 + kq*4];
  #pragma unroll
  for (int q = 0; q < 4; ++q) {
    int row = rowA + 32*q;
    int base = (kq << 9) + ((((row >> 3) ^ kq) << 3) | (row & 7));
    Bs[base]     = pB[q].x; Bs[base+128] = pB[q].y;
    Bs[base+256] = pB[q].z; Bs[base+384] = pB[q].w;
  }
  __syncthreads();

  float sqi[8];
  #pragma unroll
  for (int ri = 0; ri < 8; ++ri) sqi[ri] = sqb[i0 + rg*8 + ri];

  float d1[8], d2[8]; int j1[8], j2[8];
  #pragma unroll
  for (int ri = 0; ri < 8; ++ri) {
    d1[ri] = FLT_MAX; d2[ri] = FLT_MAX; j1[ri] = 0x7fffffff; j2[ri] = 0x7fffffff;
  }
  float acc[8][8];
  #pragma unroll
  for (int a = 0; a < 8; ++a)
    #pragma unroll
    for (int c = 0; c < 8; ++c) acc[a][c] = 0.f;

  float4 sjA = make_float4(0.f,0.f,0.f,0.f), sjB = sjA;

  #pragma unroll 1
  for (int c = 0; c < 32; ++c) {
    int cc = c & 3, jt = c >> 2;
    if (cc == 0) {                        // sq for this j-tile (used at cc==3)
      sjA = *(const float4*)&sqb[(jt << 7) + cg*4];
      sjB = *(const float4*)&sqb[(jt << 7) + 64 + cg*4];
    }
    if (c < 31) {                         // prefetch next chunk
      int cn = c + 1;
      int j0n = (cn >> 2) << 7, knn = (cn & 3) << 5;
      #pragma unroll
      for (int q = 0; q < 4; ++q)
        pB[q] = *(const float4*)&Yb[(size_t)(j0n + rowA + 32*q) * 128 + knn + kq*4];
    }
    // ---- compute 32 k on current Bs ----
    #pragma unroll
    for (int k4 = 0; k4 < 8; ++k4) {
      const float* pa = &As[((cc*8 + k4) << 9) + ((rg ^ k4) << 3)];
      const float* pb = &Bs[(k4 << 9) + ((((cg >> 1) ^ k4) << 3) | ((cg & 1) << 2))];
      #pragma unroll
      for (int kk = 0; kk < 4; ++kk) {
        float4 a0 = *(const float4*)(pa + (kk << 7));
        float4 a1 = *(const float4*)(pa + (kk << 7) + 4);
        float4 b0 = *(const float4*)(pb + (kk << 7));
        float4 b1 = *(const float4*)(pb + (kk << 7) + 64);
        float av[8] = {a0.x,a0.y,a0.z,a0.w,a1.x,a1.y,a1.z,a1.w};
        float bv[8] = {b0.x,b0.y,b0.z,b0.w,b1.x,b1.y,b1.z,b1.w};
        #pragma unroll
        for (int ri = 0; ri < 8; ++ri)
          #pragma unroll
          for (int ci = 0; ci < 8; ++ci)
            acc[ri][ci] = fmaf(av[ri], bv[ci], acc[ri][ci]);
      }
    }
    if (cc == 3) {                        // j-tile complete: fold into top-2
      int j0c = jt << 7;
      float sj[8] = {sjA.x, sjA.y, sjA.z, sjA.w, sjB.x, sjB.y, sjB.z, sjB.w};
      #pragma unroll
      for (int ri = 0; ri < 8; ++ri) {
        #pragma unroll
        for (int ci = 0; ci < 4; ++ci) {
          int j = j0c + cg*4 + ci;
          float dd = sqi[ri] + sj[ci] - 2.0f * acc[ri][ci];
          top2_update(d1[ri], j1[ri], d2[ri], j2[ri], dd, j);
        }
        #pragma unroll
        for (int ci = 0; ci < 4; ++ci) {
          int j = j0c + 64 + cg*4 + ci;
          float dd = sqi[ri] + sj[ci+4] - 2.0f * acc[ri][ci+4];
          top2_update(d1[ri], j1[ri], d2[ri], j2[ri], dd, j);
        }
      }
      #pragma unroll
      for (int a = 0; a < 8; ++a)
        #pragma unroll
        for (int cz = 0; cz < 8; ++cz) acc[a][cz] = 0.f;
    }
    __syncthreads();                      // all waves done reading Bs
    if (c < 31) {
      #pragma unroll
      for (int q = 0; q < 4; ++q) {
        int row = rowA + 32*q;
        int base = (kq << 9) + ((((row >> 3) ^ kq) << 3) | (row & 7));
        Bs[base]     = pB[q].x; Bs[base+128] = pB[q].y;
        Bs[base+256] = pB[q].z; Bs[base+384] = pB[q].w;
      }
    }
    __syncthreads();                      // stores visible for next iteration
  }

  // ---- merge across 16 cg lanes, write idx directly ----
  #pragma unroll
  for (int ri = 0; ri < 8; ++ri) {
    top2_merge_xor(d1[ri], j1[ri], d2[ri], j2[ri], 1);
    top2_merge_xor(d1[ri], j1[ri], d2[ri], j2[ri], 2);
    top2_merge_xor(d1[ri], j1[ri], d2[ri], j2[ri], 4);
    top2_merge_xor(d1[ri], j1[ri], d2[ri], j2[ri], 8);
    if (cg == 0) {
      int row = b * 1024 + i0 + rg*8 + ri;
      idx[row*2+0] = j1[ri];
      idx[row*2+1] = j2[ri];
    }
  }
}

// ---------------- edge epilogue ----------------
__global__ __launch_bounds__(256) void pn_edge_max(const float* __restrict__ U,
                                                   const float* __restrict__ V,
                                                   const int* __restrict__ idx,
                                                   const float* __restrict__ bias,
                                                   float* __restrict__ y) {
  int gid = blockIdx.x * 256 + threadIdx.x;
  int i = gid >> 5, c4 = (gid & 31) << 2;
  int base = (i >> 10) << 10;
  int j0 = idx[i*2+0], j1 = idx[i*2+1];
  float4 u  = *(const float4*)&U[(size_t)i*128 + c4];
  float4 vi = *(const float4*)&V[(size_t)i*128 + c4];
  float4 v0 = *(const float4*)&V[(size_t)(base + j0)*128 + c4];
  float4 v1 = *(const float4*)&V[(size_t)(base + j1)*128 + c4];
  float4 bb = *(const float4*)&bias[c4];
  float4 o;
  o.x = fmaxf(fmaxf(u.x + v0.x - vi.x + bb.x, u.x + v1.x - vi.x + bb.x), 0.f);
  o.y = fmaxf(fmaxf(u.y + v0.y - vi.y + bb.y, u.y + v1.y - vi.y + bb.y), 0.f);
  o.z = fmaxf(fmaxf(u.z + v0.z - vi.z + bb.z, u.z + v1.z - vi.z + bb.z), 0.f);
  o.w = fmaxf(fmaxf(u.w + v0.w - vi.w + bb.w, u.w + v1.w - vi.w + bb.w), 0.f);
  *(float4*)&y[(size_t)i*128 + c4] = o;
}

// ---------------- pooling: 4 n-chunks + combine ----------------
__global__ __launch_bounds__(384) void pn_pool1(const float* __restrict__ y1,
                                                const float* __restrict__ y2,
                                                const float* __restrict__ y3,
                                                float* __restrict__ pp) {
  int b = blockIdx.x >> 2, ch = blockIdx.x & 3, c = threadIdx.x;
  const float* src = (c < 128) ? (y1 + (size_t)b * 131072 + c)
                   : (c < 256) ? (y2 + (size_t)b * 131072 + (c - 128))
                               : (y3 + (size_t)b * 131072 + (c - 256));
  src += (size_t)ch * 256 * 128;
  float s = 0.f, mx = -FLT_MAX;
  for (int n = 0; n < 256; ++n) {
    float v = src[(size_t)n * 128];
    s += v; mx = fmaxf(mx, v);
  }
  pp[(size_t)(b*4 + ch) * 768 + c] = s;
  pp[(size_t)(b*4 + ch) * 768 + 384 + c] = mx;
}

__global__ __launch_bounds__(384) void pn_pool2(const float* __restrict__ pp,
                                                float* __restrict__ g) {
  int b = blockIdx.x, c = threadIdx.x;
  float s = 0.f, mx = -FLT_MAX;
  #pragma unroll
  for (int ch = 0; ch < 4; ++ch) {
    s += pp[(size_t)(b*4 + ch) * 768 + c];
    mx = fmaxf(mx, pp[(size_t)(b*4 + ch) * 768 + 384 + c]);
  }
  g[b*768 + c] = s * (1.0f / 1024.0f);
  g[b*768 + 384 + c] = mx;
}

// ---------------- batchnorm ----------------
__global__ __launch_bounds__(256) void pn_bn(const float* __restrict__ g,
                                             const float* __restrict__ gamma,
                                             const float* __restrict__ beta,
                                             float* __restrict__ out) {
  int c = blockIdx.x * 256 + threadIdx.x;
  float mu = 0.f;
  for (int b = 0; b < 64; ++b) mu += g[b*768 + c];
  mu *= (1.0f / 64.0f);
  float var = 0.f;
  for (int b = 0; b < 64; ++b) { float d = g[b*768 + c] - mu; var += d * d; }
  var *= (1.0f / 64.0f);
  float sc = (1.0f / sqrtf(var + 1e-5f)) * gamma[c];
  float sh = beta[c];
  for (int b = 0; b < 64; ++b) out[b*768 + c] = (g[b*768 + c] - mu) * sc + sh;
}

// ---------------- dense 768->768 (+leaky) ----------------
__global__ __launch_bounds__(256) void pn_dense(const float* __restrict__ h,
                                                const float* __restrict__ W,
                                                const float* __restrict__ bias,
                                                float* __restrict__ out) {
  int b = blockIdx.x / 3;
  int c = (blockIdx.x % 3) * 256 + threadIdx.x;
  const float* hb = h + (size_t)b * 768;
  float acc = bias[c];
  for (int w = 0; w < 768; ++w) acc = fmaf(hb[w], W[(size_t)w*768 + c], acc);
  acc = acc > 0.f ? acc : 0.01f * acc;
  out[b*768 + c] = acc;
}

// ---------------- final 768->1 ----------------
__global__ __launch_bounds__(256) void pn_out(const float* __restrict__ h,
                                              const float* __restrict__ ow,
                                              const float* __restrict__ ob,
                                              float* __restrict__ out) {
  int wid = blockIdx.x * 4 + (threadIdx.x >> 6);
  int lane = threadIdx.x & 63;
  const float* hb = h + (size_t)wid * 768;
  float s = 0.f;
  #pragma unroll
  for (int q = 0; q < 12; ++q) {
    int w = q * 64 + lane;
    s = fmaf(hb[w], ow[w], s);
  }
  #pragma unroll
  for (int m = 1; m < 64; m <<= 1) s += __shfl_xor(s, m, 64);
  if (lane == 0) out[wid] = s + ob[0];
}

extern "C" void kernel_launch(void* const* d_in, const int* in_sizes, int n_in,
                              void* d_out, int out_size, void* d_ws, size_t ws_size,
                              hipStream_t stream) {
  (void)in_sizes; (void)n_in; (void)out_size; (void)ws_size;
  const float* x     = (const float*)d_in[0];
  const float* p1w1  = (const float*)d_in[1];
  const float* p1b1  = (const float*)d_in[2];
  const float* p1w2  = (const float*)d_in[3];
  const float* p1b2  = (const float*)d_in[4];
  const float* cw    = (const float*)d_in[5];
  const float* cb    = (const float*)d_in[6];
  const float* bng   = (const float*)d_in[7];
  const float* bnb   = (const float*)d_in[8];
  const float* linw  = (const float*)d_in[9];
  const float* linb  = (const float*)d_in[10];
  const float* outw  = (const float*)d_in[11];
  const float* outb  = (const float*)d_in[12];
  float* outp = (float*)d_out;

  float* ws = (float*)d_ws;
  const size_t YSZ = (size_t)65536 * 128;
  float* y1 = ws;
  float* y2 = y1 + YSZ;
  float* y3 = y2 + YSZ;
  float* U  = y3 + YSZ;
  float* V  = U + YSZ;
  float* h1 = U;                     // conv1 scratch, dead after first gemm
  float* sq = V + YSZ;
  int*   idxb = (int*)(sq + 65536);
  float* g  = (float*)(idxb + 131072);
  float* ha = g + 49152;
  float* hb = ha + 49152;
  float* pp = hb + 49152;            // pool partials: 256*768 floats

  // --- conv1 ---
  pn_knn5<<<16384, 256, 0, stream>>>(x, idxb);
  pn_conv1_l1<<<16384, 256, 0, stream>>>(x, idxb, p1w1, p1b1, h1);
  pn_gemm128_bias<<<1024, 256, 0, stream>>>(h1, p1w2, p1b2, y1);
  // --- conv2 ---
  pn_sqnorm<<<256, 256, 0, stream>>>(y1, sq);
  pn_knn128<<<512, 256, 0, stream>>>(y1, sq, idxb);
  pn_gemm128_uv<<<1024, 256, 0, stream>>>(y1, cw, U, V);
  pn_edge_max<<<8192, 256, 0, stream>>>(U, V, idxb, cb, y2);
  // --- conv3 ---
  pn_sqnorm<<<256, 256, 0, stream>>>(y2, sq);
  pn_knn128<<<512, 256, 0, stream>>>(y2, sq, idxb);
  pn_gemm128_uv<<<1024, 256, 0, stream>>>(y2, cw + 32768, U, V);
  pn_edge_max<<<8192, 256, 0, stream>>>(U, V, idxb, cb + 128, y3);
  // --- head ---
  pn_pool1<<<256, 384, 0, stream>>>(y1, y2, y3, pp);
  pn_pool2<<<64, 384, 0, stream>>>(pp, g);
  pn_bn<<<3, 256, 0, stream>>>(g, bng, bnb, ha);
  pn_dense<<<192, 256, 0, stream>>>(ha, linw + 0*589824, linb + 0*768, hb);
  pn_dense<<<192, 256, 0, stream>>>(hb, linw + 1*589824, linb + 1*768, ha);
  pn_dense<<<192, 256, 0, stream>>>(ha, linw + 2*589824, linb + 2*768, hb);
  pn_dense<<<192, 256, 0, stream>>>(hb, linw + 3*589824, linb + 3*768, ha);
  pn_dense<<<192, 256, 0, stream>>>(ha, linw + 4*589824, linb + 4*768, hb);
  pn_out<<<16, 256, 0, stream>>>(hb, outw, outb, outp);
}

// Round 8
// 1172.439 us; speedup vs baseline: 1.9578x; 1.9578x over previous
//
#include <hip/hip_runtime.h>
#include <cfloat>

// PointNet / DGCNN: B=64, N=1024, F=5, W=128, K=2, D2=768
// R8: knn128 -> MFMA bf16-split filter (4 passes hi/lo, 16x16x32) producing
//     approx top-3/row, + exact fp32 rescore of the 3 candidates with R5's
//     bit-identical fmaf chain -> picks unchanged -> absmax 0.0.
//     fp32 Gram was latency-bound at ~29% FMA issue (R5-R7); MFMA pipe was idle.
//     LDS bf16 tiles stride 72 ushort: conflict-free b128 (8-lane-phase model).

typedef short short8 __attribute__((ext_vector_type(8)));
typedef float f32x4 __attribute__((ext_vector_type(4)));

__device__ __forceinline__ unsigned short f2bf(float f) {
  unsigned u = __float_as_uint(f);
  return (unsigned short)((u + 0x7fffu + ((u >> 16) & 1u)) >> 16);
}

__device__ __forceinline__ void top2_update(float& d1, int& j1, float& d2, int& j2,
                                            float dd, int j) {
  if (dd < d1 || (dd == d1 && j < j1)) { d2 = d1; j2 = j1; d1 = dd; j1 = j; }
  else if (dd < d2 || (dd == d2 && j < j2)) { d2 = dd; j2 = j; }
}

__device__ __forceinline__ void top2_merge_xor(float& d1, int& j1, float& d2, int& j2, int m) {
  float od1 = __shfl_xor(d1, m, 64); int oj1 = __shfl_xor(j1, m, 64);
  float od2 = __shfl_xor(d2, m, 64); int oj2 = __shfl_xor(j2, m, 64);
  bool aw = (d1 < od1) || (d1 == od1 && j1 < oj1);
  float h2d = aw ? d2 : od2;  int h2j = aw ? j2 : oj2;
  float lmd = aw ? od1 : d1;  int lmj = aw ? oj1 : j1;
  float nd1 = aw ? d1 : od1;  int nj1 = aw ? j1 : oj1;
  bool bw = (h2d < lmd) || (h2d == lmd && h2j < lmj);
  d1 = nd1; j1 = nj1;
  d2 = bw ? h2d : lmd; j2 = bw ? h2j : lmj;
}

__device__ __forceinline__ void top2_reduce_wave(float& d1, int& j1, float& d2, int& j2) {
  #pragma unroll
  for (int m = 1; m < 64; m <<= 1) top2_merge_xor(d1, j1, d2, j2, m);
}

// approx top-3 (no tie-break needed: filter only has to be a superset)
__device__ __forceinline__ void top3_update(float& d1, int& j1, float& d2, int& j2,
                                            float& d3, int& j3, float dd, int j) {
  bool c1 = dd < d1, c2 = dd < d2, c3 = dd < d3;
  float n3 = c2 ? d2 : (c3 ? dd : d3); int m3 = c2 ? j2 : (c3 ? j : j3);
  float n2 = c1 ? d1 : (c2 ? dd : d2); int m2 = c1 ? j1 : (c2 ? j : j2);
  d1 = c1 ? dd : d1; j1 = c1 ? j : j1;
  d2 = n2; j2 = m2; d3 = n3; j3 = m3;
}

// ---------------- KNN on 5-dim x ----------------
__global__ __launch_bounds__(256) void pn_knn5(const float* __restrict__ x,
                                               int* __restrict__ idx) {
  __shared__ float xs[5120];
  int t = threadIdx.x;
  int b = blockIdx.x >> 8;
  int r0 = (blockIdx.x & 255) * 4;
  const float4* xb4 = (const float4*)(x + (size_t)b * 5120);
  #pragma unroll
  for (int s = 0; s < 5; ++s) ((float4*)xs)[t + 256 * s] = xb4[t + 256 * s];
  __syncthreads();
  int wv = t >> 6, lane = t & 63;
  int i = r0 + wv;
  float x0 = xs[i*5+0], x1 = xs[i*5+1], x2 = xs[i*5+2], x3 = xs[i*5+3], x4 = xs[i*5+4];
  float d1 = FLT_MAX, d2 = FLT_MAX; int j1 = 0x7fffffff, j2 = 0x7fffffff;
  for (int tS = 0; tS < 16; ++tS) {
    int j = tS * 64 + lane;
    const float* xj = &xs[j * 5];
    float f0 = xj[0] - x0, f1 = xj[1] - x1, f2 = xj[2] - x2, f3 = xj[3] - x3, f4 = xj[4] - x4;
    float dd = f0*f0 + f1*f1 + f2*f2 + f3*f3 + f4*f4;
    top2_update(d1, j1, d2, j2, dd, j);
  }
  top2_reduce_wave(d1, j1, d2, j2);
  if (lane == 0) {
    int r = b * 1024 + i;
    idx[r*2+0] = j1; idx[r*2+1] = j2;
  }
}

// ---------------- conv1 layer1: x rows staged in LDS ----------------
__global__ __launch_bounds__(256) void pn_conv1_l1(const float* __restrict__ x,
                                                   const int* __restrict__ idx,
                                                   const float* __restrict__ w1,
                                                   const float* __restrict__ b1,
                                                   float* __restrict__ h1) {
  __shared__ float Ws[1280];
  __shared__ float Bs[128];
  __shared__ float xs[8][10];
  __shared__ int   js[8];
  int t = threadIdx.x;
  int r0 = blockIdx.x * 8;
  for (int s = t; s < 1280; s += 256) Ws[s] = w1[s];
  if (t < 128) Bs[t] = b1[t];
  if (t < 8) {
    int r = r0 + t; int i = r >> 1, k = r & 1;
    js[t] = idx[i*2 + k];
  }
  __syncthreads();
  if (t < 80) {
    int row = t / 10, f = t % 10;
    int r = r0 + row; int i = r >> 1;
    if (f < 5) xs[row][f] = x[(size_t)i * 5 + f];
    else {
      int jrow = ((i >> 10) << 10) + js[row];
      xs[row][f] = x[(size_t)jrow * 5 + (f - 5)];
    }
  }
  __syncthreads();
  int c = t & 127, rr = t >> 7;
  #pragma unroll
  for (int s = 0; s < 4; ++s) {
    int row = s * 2 + rr;
    float acc = Bs[c];
    #pragma unroll
    for (int f = 0; f < 5; ++f) {
      float a = xs[row][f];
      float d = xs[row][5+f] - a;
      acc = fmaf(a, Ws[f*128 + c], acc);
      acc = fmaf(d, Ws[(5+f)*128 + c], acc);
    }
    h1[(size_t)(r0 + row) * 128 + c] = fmaxf(acc, 0.0f);
  }
}

// ---------------- GEMM core: A[128 rows] @ W[128,128] ----------------
template<bool RELU, bool PAIRMAX>
__device__ __forceinline__ void gemm128_core(int bid, const float* __restrict__ A,
                                             const float* __restrict__ W,
                                             const float* __restrict__ bias,
                                             float* __restrict__ out) {
  __shared__ __align__(16) float As[4096];
  __shared__ __align__(16) float Wsb[32][132];
  int t = threadIdx.x;
  int rg = t >> 4;
  int cg = t & 15;
  float acc[8][8];
  #pragma unroll
  for (int a = 0; a < 8; ++a)
    #pragma unroll
    for (int b = 0; b < 8; ++b) acc[a][b] = 0.f;
  size_t r0 = (size_t)bid * 128;
  int ra = t >> 1, hf = t & 1;
  int wb = t >> 3, cp = t & 7;
  for (int w0 = 0; w0 < 128; w0 += 32) {
    const float* asrc = A + (r0 + ra) * 128 + w0 + hf * 16;
    #pragma unroll
    for (int q = 0; q < 4; ++q) {
      float4 v = ((const float4*)asrc)[q];
      int base = ((hf << 4) + (q << 2)) * 128 +
                 ((((ra >> 3) ^ ((hf << 2) + q)) << 3) | (ra & 7));
      As[base] = v.x; As[base+128] = v.y; As[base+256] = v.z; As[base+384] = v.w;
    }
    const float* wsrc = W + (size_t)(w0 + wb) * 128 + cp * 16;
    #pragma unroll
    for (int q = 0; q < 4; ++q)
      *(float4*)&Wsb[wb][cp*16 + q*4] = ((const float4*)wsrc)[q];
    __syncthreads();
    #pragma unroll
    for (int k4 = 0; k4 < 8; ++k4) {
      const float* pa = &As[(k4 << 9) + ((rg ^ k4) << 3)];
      #pragma unroll
      for (int kk = 0; kk < 4; ++kk) {
        int w = (k4 << 2) + kk;
        float4 a0 = *(const float4*)(pa + (kk << 7));
        float4 a1 = *(const float4*)(pa + (kk << 7) + 4);
        float4 wv0 = *(const float4*)&Wsb[w][cg*4];
        float4 wv1 = *(const float4*)&Wsb[w][64 + cg*4];
        float av[8] = {a0.x,a0.y,a0.z,a0.w,a1.x,a1.y,a1.z,a1.w};
        float wv[8] = {wv0.x,wv0.y,wv0.z,wv0.w,wv1.x,wv1.y,wv1.z,wv1.w};
        #pragma unroll
        for (int ri = 0; ri < 8; ++ri)
          #pragma unroll
          for (int ci = 0; ci < 8; ++ci)
            acc[ri][ci] = fmaf(av[ri], wv[ci], acc[ri][ci]);
      }
    }
    __syncthreads();
  }
  float blo[4], bhi[4];
  #pragma unroll
  for (int ci = 0; ci < 4; ++ci) {
    blo[ci] = bias ? bias[cg*4 + ci] : 0.f;
    bhi[ci] = bias ? bias[64 + cg*4 + ci] : 0.f;
  }
  if (PAIRMAX) {
    #pragma unroll
    for (int ri = 0; ri < 8; ri += 2) {
      size_t orow = (r0 + rg*8 + ri) >> 1;
      float lo[4], hi[4];
      #pragma unroll
      for (int ci = 0; ci < 4; ++ci) {
        float v0 = acc[ri][ci]   + blo[ci];
        float v1 = acc[ri+1][ci] + blo[ci];
        lo[ci] = fmaxf(fmaxf(v0, v1), 0.f);
        float w0v = acc[ri][ci+4]   + bhi[ci];
        float w1v = acc[ri+1][ci+4] + bhi[ci];
        hi[ci] = fmaxf(fmaxf(w0v, w1v), 0.f);
      }
      *(float4*)&out[orow*128 + cg*4]      = *(float4*)lo;
      *(float4*)&out[orow*128 + 64 + cg*4] = *(float4*)hi;
    }
  } else {
    #pragma unroll
    for (int ri = 0; ri < 8; ++ri) {
      size_t row = r0 + rg*8 + ri;
      float lo[4], hi[4];
      #pragma unroll
      for (int ci = 0; ci < 4; ++ci) {
        float v0 = acc[ri][ci]   + blo[ci];
        float v1 = acc[ri][ci+4] + bhi[ci];
        lo[ci] = RELU ? fmaxf(v0, 0.f) : v0;
        hi[ci] = RELU ? fmaxf(v1, 0.f) : v1;
      }
      *(float4*)&out[row*128 + cg*4]      = *(float4*)lo;
      *(float4*)&out[row*128 + 64 + cg*4] = *(float4*)hi;
    }
  }
}

__global__ __launch_bounds__(256) void pn_gemm128_bias(const float* __restrict__ A,
                                                       const float* __restrict__ W,
                                                       const float* __restrict__ bias,
                                                       float* __restrict__ out) {
  gemm128_core<true, true>(blockIdx.x, A, W, bias, out);
}

__global__ __launch_bounds__(256) void pn_gemm128_uv(const float* __restrict__ A,
                                                     const float* __restrict__ Wb,
                                                     float* __restrict__ U,
                                                     float* __restrict__ V) {
  int which = blockIdx.x >> 9;
  gemm128_core<false, false>(blockIdx.x & 511, A, Wb + (which << 14), nullptr,
                             which ? V : U);
}

// ---------------- row squared norms ----------------
__global__ __launch_bounds__(256) void pn_sqnorm(const float* __restrict__ y,
                                                 float* __restrict__ sq) {
  int r = blockIdx.x * 256 + threadIdx.x;
  const float4* p = (const float4*)(y + (size_t)r * 128);
  float s = 0.f;
  #pragma unroll
  for (int q = 0; q < 32; ++q) {
    float4 v = p[q];
    s += v.x*v.x + v.y*v.y + v.z*v.z + v.w*v.w;
  }
  sq[r] = s;
}

// ---------------- split y -> bf16 hi/lo ----------------
__global__ __launch_bounds__(256) void pn_split(const float* __restrict__ y,
                                                unsigned short* __restrict__ yh,
                                                unsigned short* __restrict__ yl) {
  int gid = blockIdx.x * 256 + threadIdx.x;
  float4 v = ((const float4*)y)[gid];
  ushort4 h, l;
  h.x = f2bf(v.x); l.x = f2bf(v.x - __uint_as_float((unsigned)h.x << 16));
  h.y = f2bf(v.y); l.y = f2bf(v.y - __uint_as_float((unsigned)h.y << 16));
  h.z = f2bf(v.z); l.z = f2bf(v.z - __uint_as_float((unsigned)h.z << 16));
  h.w = f2bf(v.w); l.w = f2bf(v.w - __uint_as_float((unsigned)h.w << 16));
  ((ushort4*)yh)[gid] = h;
  ((ushort4*)yl)[gid] = l;
}

// ---------------- KNN-128 MFMA filter: approx top-3 per row ----------------
// grid = 64 ev x 8 itiles = 512 blocks (2/CU). i-tile 128; j chunks of 128;
// k chunks of 64. 4 mfma passes (hh, hl, lh, ll) -> approx err ~3e-5.
__global__ __launch_bounds__(256) void pn_knn_mfma(const unsigned short* __restrict__ Yh,
                                                   const unsigned short* __restrict__ Yl,
                                                   const float* __restrict__ sqn,
                                                   int4* __restrict__ cand) {
  __shared__ __align__(16) unsigned short Ah[128*72];
  __shared__ __align__(16) unsigned short Al[128*72];
  __shared__ __align__(16) unsigned short Bh[128*72];
  __shared__ __align__(16) unsigned short Bl[128*72];
  __shared__ float sqs[1024];
  int t = threadIdx.x;
  int b  = blockIdx.x >> 3;
  int it = blockIdx.x & 7;
  int i0 = it * 128;
  int lane = t & 63, wave = t >> 6;
  int quad = lane >> 4, l16 = lane & 15;
  #pragma unroll
  for (int s = 0; s < 4; ++s) sqs[t + 256*s] = sqn[b*1024 + t + 256*s];

  float D1[8], D2[8], D3[8]; int J1[8], J2[8], J3[8];
  #pragma unroll
  for (int r = 0; r < 8; ++r) {
    D1[r] = FLT_MAX; D2[r] = FLT_MAX; D3[r] = FLT_MAX;
    J1[r] = 0x7fffffff; J2[r] = 0x7fffffff; J3[r] = 0x7fffffff;
  }

  int sr = t >> 1, shf = t & 1;   // staging: row 0..127, half 0..1

  #pragma unroll 1
  for (int jc = 0; jc < 8; ++jc) {
    f32x4 acc[2][8];
    #pragma unroll
    for (int s = 0; s < 2; ++s)
      #pragma unroll
      for (int js = 0; js < 8; ++js)
        acc[s][js] = (f32x4){0.f, 0.f, 0.f, 0.f};

    #pragma unroll 1
    for (int kc = 0; kc < 2; ++kc) {
      __syncthreads();
      {
        size_t ga = (size_t)(b*1024 + i0 + sr) * 128 + kc*64 + shf*32;
        size_t gb = (size_t)(b*1024 + jc*128 + sr) * 128 + kc*64 + shf*32;
        const uint4* sAh = (const uint4*)&Yh[ga];
        const uint4* sAl = (const uint4*)&Yl[ga];
        const uint4* sBh = (const uint4*)&Yh[gb];
        const uint4* sBl = (const uint4*)&Yl[gb];
        uint4* dAh = (uint4*)&Ah[sr*72 + shf*32];
        uint4* dAl = (uint4*)&Al[sr*72 + shf*32];
        uint4* dBh = (uint4*)&Bh[sr*72 + shf*32];
        uint4* dBl = (uint4*)&Bl[sr*72 + shf*32];
        #pragma unroll
        for (int q = 0; q < 4; ++q) {
          dAh[q] = sAh[q]; dAl[q] = sAl[q];
          dBh[q] = sBh[q]; dBl[q] = sBl[q];
        }
      }
      __syncthreads();
      #pragma unroll
      for (int ks = 0; ks < 2; ++ks) {
        int ko = ks*32 + quad*8;
        short8 ah0 = *(const short8*)&Ah[(wave*32 + l16)*72 + ko];
        short8 ah1 = *(const short8*)&Ah[(wave*32 + 16 + l16)*72 + ko];
        short8 al0 = *(const short8*)&Al[(wave*32 + l16)*72 + ko];
        short8 al1 = *(const short8*)&Al[(wave*32 + 16 + l16)*72 + ko];
        #pragma unroll
        for (int js = 0; js < 8; ++js) {
          short8 bh = *(const short8*)&Bh[(js*16 + l16)*72 + ko];
          short8 bl = *(const short8*)&Bl[(js*16 + l16)*72 + ko];
          acc[0][js] = __builtin_amdgcn_mfma_f32_16x16x32_bf16(ah0, bh, acc[0][js], 0, 0, 0);
          acc[0][js] = __builtin_amdgcn_mfma_f32_16x16x32_bf16(ah0, bl, acc[0][js], 0, 0, 0);
          acc[0][js] = __builtin_amdgcn_mfma_f32_16x16x32_bf16(al0, bh, acc[0][js], 0, 0, 0);
          acc[0][js] = __builtin_amdgcn_mfma_f32_16x16x32_bf16(al0, bl, acc[0][js], 0, 0, 0);
          acc[1][js] = __builtin_amdgcn_mfma_f32_16x16x32_bf16(ah1, bh, acc[1][js], 0, 0, 0);
          acc[1][js] = __builtin_amdgcn_mfma_f32_16x16x32_bf16(ah1, bl, acc[1][js], 0, 0, 0);
          acc[1][js] = __builtin_amdgcn_mfma_f32_16x16x32_bf16(al1, bh, acc[1][js], 0, 0, 0);
          acc[1][js] = __builtin_amdgcn_mfma_f32_16x16x32_bf16(al1, bl, acc[1][js], 0, 0, 0);
        }
      }
    }
    // fold: ranking key sqj - 2g (sqi constant per row -> same order)
    #pragma unroll
    for (int js = 0; js < 8; ++js) {
      int jg = jc*128 + js*16 + l16;
      float sj = sqs[jg];
      #pragma unroll
      for (int s = 0; s < 2; ++s)
        #pragma unroll
        for (int r = 0; r < 4; ++r) {
          float dd = fmaf(-2.f, acc[s][js][r], sj);
          int id8 = s*4 + r;
          top3_update(D1[id8], J1[id8], D2[id8], J2[id8], D3[id8], J3[id8], dd, jg);
        }
    }
  }

  // merge across the 16 j-lanes (xor < 16 stays within the quad's 16 lanes)
  #pragma unroll
  for (int id8 = 0; id8 < 8; ++id8) {
    #pragma unroll
    for (int m = 1; m < 16; m <<= 1) {
      float o1 = __shfl_xor(D1[id8], m, 64); int p1 = __shfl_xor(J1[id8], m, 64);
      float o2 = __shfl_xor(D2[id8], m, 64); int p2 = __shfl_xor(J2[id8], m, 64);
      float o3 = __shfl_xor(D3[id8], m, 64); int p3 = __shfl_xor(J3[id8], m, 64);
      top3_update(D1[id8], J1[id8], D2[id8], J2[id8], D3[id8], J3[id8], o1, p1);
      top3_update(D1[id8], J1[id8], D2[id8], J2[id8], D3[id8], J3[id8], o2, p2);
      top3_update(D1[id8], J1[id8], D2[id8], J2[id8], D3[id8], J3[id8], o3, p3);
    }
    if (l16 == 0) {
      int s = id8 >> 2, r = id8 & 3;
      int row = b*1024 + i0 + wave*32 + s*16 + quad*4 + r;
      cand[row] = make_int4(J1[id8], J2[id8], J3[id8], 0x7fffffff);
    }
  }
}

// ---------------- exact rescore of 3 candidates (R5's bit-identical chain) ---
__global__ __launch_bounds__(256) void pn_knn_rescore(const float* __restrict__ Y,
                                                      const float* __restrict__ sqn,
                                                      const int4* __restrict__ cand,
                                                      int* __restrict__ idx) {
  int gid = blockIdx.x * 256 + threadIdx.x;
  int row = gid >> 2, c = gid & 3;
  int base = (row >> 10) << 10;
  int4 cd = cand[row];
  int cj = (c == 0) ? cd.x : (c == 1) ? cd.y : cd.z;   // c==3 -> cd.z dup, masked below
  const float4* yi = (const float4*)&Y[(size_t)row * 128];
  const float4* yj = (const float4*)&Y[(size_t)(base + cj) * 128];
  float acc = 0.f;
  #pragma unroll 8
  for (int q = 0; q < 32; ++q) {
    float4 a = yi[q], bq = yj[q];
    acc = fmaf(a.x, bq.x, acc);
    acc = fmaf(a.y, bq.y, acc);
    acc = fmaf(a.z, bq.z, acc);
    acc = fmaf(a.w, bq.w, acc);
  }
  float dd = sqn[row] + sqn[base + cj] - 2.0f * acc;
  int jv = cj;
  if (c == 3) { dd = FLT_MAX; jv = 0x7fffffff; }
  float d1 = dd, d2 = FLT_MAX; int j1 = jv, j2 = 0x7fffffff;
  top2_merge_xor(d1, j1, d2, j2, 1);
  top2_merge_xor(d1, j1, d2, j2, 2);
  if (c == 0) {
    idx[row*2+0] = j1;
    idx[row*2+1] = j2;
  }
}

// ---------------- edge epilogue ----------------
__global__ __launch_bounds__(256) void pn_edge_max(const float* __restrict__ U,
                                                   const float* __restrict__ V,
                                                   const int* __restrict__ idx,
                                                   const float* __restrict__ bias,
                                                   float* __restrict__ y) {
  int gid = blockIdx.x * 256 + threadIdx.x;
  int i = gid >> 5, c4 = (gid & 31) << 2;
  int base = (i >> 10) << 10;
  int j0 = idx[i*2+0], j1 = idx[i*2+1];
  float4 u  = *(const float4*)&U[(size_t)i*128 + c4];
  float4 vi = *(const float4*)&V[(size_t)i*128 + c4];
  float4 v0 = *(const float4*)&V[(size_t)(base + j0)*128 + c4];
  float4 v1 = *(const float4*)&V[(size_t)(base + j1)*128 + c4];
  float4 bb = *(const float4*)&bias[c4];
  float4 o;
  o.x = fmaxf(fmaxf(u.x + v0.x - vi.x + bb.x, u.x + v1.x - vi.x + bb.x), 0.f);
  o.y = fmaxf(fmaxf(u.y + v0.y - vi.y + bb.y, u.y + v1.y - vi.y + bb.y), 0.f);
  o.z = fmaxf(fmaxf(u.z + v0.z - vi.z + bb.z, u.z + v1.z - vi.z + bb.z), 0.f);
  o.w = fmaxf(fmaxf(u.w + v0.w - vi.w + bb.w, u.w + v1.w - vi.w + bb.w), 0.f);
  *(float4*)&y[(size_t)i*128 + c4] = o;
}

// ---------------- pooling: 4 n-chunks + combine ----------------
__global__ __launch_bounds__(384) void pn_pool1(const float* __restrict__ y1,
                                                const float* __restrict__ y2,
                                                const float* __restrict__ y3,
                                                float* __restrict__ pp) {
  int b = blockIdx.x >> 2, ch = blockIdx.x & 3, c = threadIdx.x;
  const float* src = (c < 128) ? (y1 + (size_t)b * 131072 + c)
                   : (c < 256) ? (y2 + (size_t)b * 131072 + (c - 128))
                               : (y3 + (size_t)b * 131072 + (c - 256));
  src += (size_t)ch * 256 * 128;
  float s = 0.f, mx = -FLT_MAX;
  for (int n = 0; n < 256; ++n) {
    float v = src[(size_t)n * 128];
    s += v; mx = fmaxf(mx, v);
  }
  pp[(size_t)(b*4 + ch) * 768 + c] = s;
  pp[(size_t)(b*4 + ch) * 768 + 384 + c] = mx;
}

__global__ __launch_bounds__(384) void pn_pool2(const float* __restrict__ pp,
                                                float* __restrict__ g) {
  int b = blockIdx.x, c = threadIdx.x;
  float s = 0.f, mx = -FLT_MAX;
  #pragma unroll
  for (int ch = 0; ch < 4; ++ch) {
    s += pp[(size_t)(b*4 + ch) * 768 + c];
    mx = fmaxf(mx, pp[(size_t)(b*4 + ch) * 768 + 384 + c]);
  }
  g[b*768 + c] = s * (1.0f / 1024.0f);
  g[b*768 + 384 + c] = mx;
}

// ---------------- batchnorm ----------------
__global__ __launch_bounds__(256) void pn_bn(const float* __restrict__ g,
                                             const float* __restrict__ gamma,
                                             const float* __restrict__ beta,
                                             float* __restrict__ out) {
  int c = blockIdx.x * 256 + threadIdx.x;
  float mu = 0.f;
  for (int b = 0; b < 64; ++b) mu += g[b*768 + c];
  mu *= (1.0f / 64.0f);
  float var = 0.f;
  for (int b = 0; b < 64; ++b) { float d = g[b*768 + c] - mu; var += d * d; }
  var *= (1.0f / 64.0f);
  float sc = (1.0f / sqrtf(var + 1e-5f)) * gamma[c];
  float sh = beta[c];
  for (int b = 0; b < 64; ++b) out[b*768 + c] = (g[b*768 + c] - mu) * sc + sh;
}

// ---------------- dense 768->768 (+leaky) ----------------
__global__ __launch_bounds__(256) void pn_dense(const float* __restrict__ h,
                                                const float* __restrict__ W,
                                                const float* __restrict__ bias,
                                                float* __restrict__ out) {
  int b = blockIdx.x / 3;
  int c = (blockIdx.x % 3) * 256 + threadIdx.x;
  const float* hb = h + (size_t)b * 768;
  float acc = bias[c];
  for (int w = 0; w < 768; ++w) acc = fmaf(hb[w], W[(size_t)w*768 + c], acc);
  acc = acc > 0.f ? acc : 0.01f * acc;
  out[b*768 + c] = acc;
}

// ---------------- final 768->1 ----------------
__global__ __launch_bounds__(256) void pn_out(const float* __restrict__ h,
                                              const float* __restrict__ ow,
                                              const float* __restrict__ ob,
                                              float* __restrict__ out) {
  int wid = blockIdx.x * 4 + (threadIdx.x >> 6);
  int lane = threadIdx.x & 63;
  const float* hb = h + (size_t)wid * 768;
  float s = 0.f;
  #pragma unroll
  for (int q = 0; q < 12; ++q) {
    int w = q * 64 + lane;
    s = fmaf(hb[w], ow[w], s);
  }
  #pragma unroll
  for (int m = 1; m < 64; m <<= 1) s += __shfl_xor(s, m, 64);
  if (lane == 0) out[wid] = s + ob[0];
}

extern "C" void kernel_launch(void* const* d_in, const int* in_sizes, int n_in,
                              void* d_out, int out_size, void* d_ws, size_t ws_size,
                              hipStream_t stream) {
  (void)in_sizes; (void)n_in; (void)out_size; (void)ws_size;
  const float* x     = (const float*)d_in[0];
  const float* p1w1  = (const float*)d_in[1];
  const float* p1b1  = (const float*)d_in[2];
  const float* p1w2  = (const float*)d_in[3];
  const float* p1b2  = (const float*)d_in[4];
  const float* cw    = (const float*)d_in[5];
  const float* cb    = (const float*)d_in[6];
  const float* bng   = (const float*)d_in[7];
  const float* bnb   = (const float*)d_in[8];
  const float* linw  = (const float*)d_in[9];
  const float* linb  = (const float*)d_in[10];
  const float* outw  = (const float*)d_in[11];
  const float* outb  = (const float*)d_in[12];
  float* outp = (float*)d_out;

  float* ws = (float*)d_ws;
  const size_t YSZ = (size_t)65536 * 128;
  float* y1 = ws;
  float* y2 = y1 + YSZ;
  float* y3 = y2 + YSZ;
  float* U  = y3 + YSZ;
  float* V  = U + YSZ;
  float* h1 = U;                         // conv1 scratch, dead after gemm_bias
  unsigned short* yh = (unsigned short*)U;           // 16 MB, dead before U write
  unsigned short* yl = (unsigned short*)U + YSZ;     // second 16 MB of U region
  int4* cand = (int4*)V;                 // 1 MB, dead before V write
  float* sq = V + YSZ;
  int*   idxb = (int*)(sq + 65536);
  float* g  = (float*)(idxb + 131072);
  float* ha = g + 49152;
  float* hb = ha + 49152;
  float* pp = hb + 49152;                // pool partials: 256*768 floats

  // --- conv1 ---
  pn_knn5<<<16384, 256, 0, stream>>>(x, idxb);
  pn_conv1_l1<<<16384, 256, 0, stream>>>(x, idxb, p1w1, p1b1, h1);
  pn_gemm128_bias<<<1024, 256, 0, stream>>>(h1, p1w2, p1b2, y1);
  // --- conv2 ---
  pn_sqnorm<<<256, 256, 0, stream>>>(y1, sq);
  pn_split<<<8192, 256, 0, stream>>>(y1, yh, yl);
  pn_knn_mfma<<<512, 256, 0, stream>>>(yh, yl, sq, cand);
  pn_knn_rescore<<<1024, 256, 0, stream>>>(y1, sq, cand, idxb);
  pn_gemm128_uv<<<1024, 256, 0, stream>>>(y1, cw, U, V);
  pn_edge_max<<<8192, 256, 0, stream>>>(U, V, idxb, cb, y2);
  // --- conv3 ---
  pn_sqnorm<<<256, 256, 0, stream>>>(y2, sq);
  pn_split<<<8192, 256, 0, stream>>>(y2, yh, yl);
  pn_knn_mfma<<<512, 256, 0, stream>>>(yh, yl, sq, cand);
  pn_knn_rescore<<<1024, 256, 0, stream>>>(y2, sq, cand, idxb);
  pn_gemm128_uv<<<1024, 256, 0, stream>>>(y2, cw + 32768, U, V);
  pn_edge_max<<<8192, 256, 0, stream>>>(U, V, idxb, cb + 128, y3);
  // --- head ---
  pn_pool1<<<256, 384, 0, stream>>>(y1, y2, y3, pp);
  pn_pool2<<<64, 384, 0, stream>>>(pp, g);
  pn_bn<<<3, 256, 0, stream>>>(g, bng, bnb, ha);
  pn_dense<<<192, 256, 0, stream>>>(ha, linw + 0*589824, linb + 0*768, hb);
  pn_dense<<<192, 256, 0, stream>>>(hb, linw + 1*589824, linb + 1*768, ha);
  pn_dense<<<192, 256, 0, stream>>>(ha, linw + 2*589824, linb + 2*768, hb);
  pn_dense<<<192, 256, 0, stream>>>(hb, linw + 3*589824, linb + 3*768, ha);
  pn_dense<<<192, 256, 0, stream>>>(ha, linw + 4*589824, linb + 4*768, hb);
  pn_out<<<16, 256, 0, stream>>>(hb, outw, outb, outp);
}

// Round 9
// 1152.278 us; speedup vs baseline: 1.9921x; 1.0175x over previous
//
#include <hip/hip_runtime.h>
#include <cfloat>

// PointNet / DGCNN: B=64, N=1024, F=5, W=128, K=2, D2=768
// R9: pn_knn5 rewritten: 8 j-slices, thread-owned rows, wave-uniform LDS
//     broadcast xj, register top-2, pn_knn_merge for slices (R8's knn5 was
//     shuffle/DS-bound: 237us at 23% VALUBusy). conv1_l1 32 rows/block.
//     pn_dense 4-acc ILP (breaks 768-dep fma chain; absmax ~1e-5 ok).
//     MFMA knn filter + exact rescore unchanged from R8.

typedef short short8 __attribute__((ext_vector_type(8)));
typedef float f32x4 __attribute__((ext_vector_type(4)));

__device__ __forceinline__ unsigned short f2bf(float f) {
  unsigned u = __float_as_uint(f);
  return (unsigned short)((u + 0x7fffu + ((u >> 16) & 1u)) >> 16);
}

__device__ __forceinline__ void top2_update(float& d1, int& j1, float& d2, int& j2,
                                            float dd, int j) {
  if (dd < d1 || (dd == d1 && j < j1)) { d2 = d1; j2 = j1; d1 = dd; j1 = j; }
  else if (dd < d2 || (dd == d2 && j < j2)) { d2 = dd; j2 = j; }
}

__device__ __forceinline__ void top2_merge_xor(float& d1, int& j1, float& d2, int& j2, int m) {
  float od1 = __shfl_xor(d1, m, 64); int oj1 = __shfl_xor(j1, m, 64);
  float od2 = __shfl_xor(d2, m, 64); int oj2 = __shfl_xor(j2, m, 64);
  bool aw = (d1 < od1) || (d1 == od1 && j1 < oj1);
  float h2d = aw ? d2 : od2;  int h2j = aw ? j2 : oj2;
  float lmd = aw ? od1 : d1;  int lmj = aw ? oj1 : j1;
  float nd1 = aw ? d1 : od1;  int nj1 = aw ? j1 : oj1;
  bool bw = (h2d < lmd) || (h2d == lmd && h2j < lmj);
  d1 = nd1; j1 = nj1;
  d2 = bw ? h2d : lmd; j2 = bw ? h2j : lmj;
}

// approx top-3 (filter only needs to be a superset)
__device__ __forceinline__ void top3_update(float& d1, int& j1, float& d2, int& j2,
                                            float& d3, int& j3, float dd, int j) {
  bool c1 = dd < d1, c2 = dd < d2, c3 = dd < d3;
  float n3 = c2 ? d2 : (c3 ? dd : d3); int m3 = c2 ? j2 : (c3 ? j : j3);
  float n2 = c1 ? d1 : (c2 ? dd : d2); int m2 = c1 ? j1 : (c2 ? j : j2);
  d1 = c1 ? dd : d1; j1 = c1 ? j : j1;
  d2 = n2; j2 = m2; d3 = n3; j3 = m3;
}

// ---------------- KNN on 5-dim x: 8 j-slices, 4 rows/thread ----------------
// grid = 64 ev x 8 jslices = 512 blocks (2/CU).
__global__ __launch_bounds__(256) void pn_knn5(const float* __restrict__ x,
                                               int4* __restrict__ cand) {
  __shared__ float xs[5120];
  int t = threadIdx.x;
  int b  = blockIdx.x >> 3;
  int js = blockIdx.x & 7;
  const float4* xb4 = (const float4*)(x + (size_t)b * 5120);
  #pragma unroll
  for (int s = 0; s < 5; ++s) ((float4*)xs)[t + 256 * s] = xb4[t + 256 * s];
  __syncthreads();
  float xi[4][5];
  #pragma unroll
  for (int q = 0; q < 4; ++q)
    #pragma unroll
    for (int f = 0; f < 5; ++f) xi[q][f] = xs[(t + 256*q)*5 + f];
  float d1[4], d2[4]; int j1[4], j2[4];
  #pragma unroll
  for (int q = 0; q < 4; ++q) {
    d1[q] = FLT_MAX; d2[q] = FLT_MAX; j1[q] = 0x7fffffff; j2[q] = 0x7fffffff;
  }
  int j0 = js * 128;
  #pragma unroll 4
  for (int jj = 0; jj < 128; ++jj) {
    int j = j0 + jj;
    const float* xj = &xs[j * 5];          // wave-uniform -> LDS broadcast
    float xj0 = xj[0], xj1 = xj[1], xj2 = xj[2], xj3 = xj[3], xj4 = xj[4];
    #pragma unroll
    for (int q = 0; q < 4; ++q) {
      float f0 = xj0 - xi[q][0], f1 = xj1 - xi[q][1], f2 = xj2 - xi[q][2],
            f3 = xj3 - xi[q][3], f4 = xj4 - xi[q][4];
      float dd = f0*f0 + f1*f1 + f2*f2 + f3*f3 + f4*f4;
      top2_update(d1[q], j1[q], d2[q], j2[q], dd, j);
    }
  }
  #pragma unroll
  for (int q = 0; q < 4; ++q) {
    int row = b * 1024 + t + 256*q;
    cand[(size_t)js * 65536 + row] =
      make_int4(__float_as_int(d1[q]), __float_as_int(d2[q]), j1[q], j2[q]);
  }
}

__global__ __launch_bounds__(256) void pn_knn_merge(const int4* __restrict__ cand,
                                                    int nslice,
                                                    int* __restrict__ idx) {
  int r = blockIdx.x * 256 + threadIdx.x;
  float d1 = FLT_MAX, d2 = FLT_MAX; int j1 = 0x7fffffff, j2 = 0x7fffffff;
  for (int s = 0; s < nslice; ++s) {
    int4 c = cand[(size_t)s * 65536 + r];
    top2_update(d1, j1, d2, j2, __int_as_float(c.x), c.z);
    top2_update(d1, j1, d2, j2, __int_as_float(c.y), c.w);
  }
  idx[r*2+0] = j1; idx[r*2+1] = j2;
}

// ---------------- conv1 layer1: 32 rows/block ----------------
__global__ __launch_bounds__(256) void pn_conv1_l1(const float* __restrict__ x,
                                                   const int* __restrict__ idx,
                                                   const float* __restrict__ w1,
                                                   const float* __restrict__ b1,
                                                   float* __restrict__ h1) {
  __shared__ float Ws[1280];
  __shared__ float Bs[128];
  __shared__ float xs[32][10];
  __shared__ int   js[32];
  int t = threadIdx.x;
  int r0 = blockIdx.x * 32;
  for (int s = t; s < 1280; s += 256) Ws[s] = w1[s];
  if (t < 128) Bs[t] = b1[t];
  if (t < 32) {
    int r = r0 + t; int i = r >> 1, k = r & 1;
    js[t] = idx[i*2 + k];
  }
  __syncthreads();
  for (int s = t; s < 320; s += 256) {
    int row = s / 10, f = s % 10;
    int r = r0 + row; int i = r >> 1;
    if (f < 5) xs[row][f] = x[(size_t)i * 5 + f];
    else {
      int jrow = ((i >> 10) << 10) + js[row];
      xs[row][f] = x[(size_t)jrow * 5 + (f - 5)];
    }
  }
  __syncthreads();
  int c = t & 127, rr = t >> 7;
  #pragma unroll
  for (int s = 0; s < 16; ++s) {
    int row = s * 2 + rr;
    float acc = Bs[c];
    #pragma unroll
    for (int f = 0; f < 5; ++f) {
      float a = xs[row][f];
      float d = xs[row][5+f] - a;
      acc = fmaf(a, Ws[f*128 + c], acc);
      acc = fmaf(d, Ws[(5+f)*128 + c], acc);
    }
    h1[(size_t)(r0 + row) * 128 + c] = fmaxf(acc, 0.0f);
  }
}

// ---------------- GEMM core: A[128 rows] @ W[128,128] ----------------
template<bool RELU, bool PAIRMAX>
__device__ __forceinline__ void gemm128_core(int bid, const float* __restrict__ A,
                                             const float* __restrict__ W,
                                             const float* __restrict__ bias,
                                             float* __restrict__ out) {
  __shared__ __align__(16) float As[4096];
  __shared__ __align__(16) float Wsb[32][132];
  int t = threadIdx.x;
  int rg = t >> 4;
  int cg = t & 15;
  float acc[8][8];
  #pragma unroll
  for (int a = 0; a < 8; ++a)
    #pragma unroll
    for (int b = 0; b < 8; ++b) acc[a][b] = 0.f;
  size_t r0 = (size_t)bid * 128;
  int ra = t >> 1, hf = t & 1;
  int wb = t >> 3, cp = t & 7;
  for (int w0 = 0; w0 < 128; w0 += 32) {
    const float* asrc = A + (r0 + ra) * 128 + w0 + hf * 16;
    #pragma unroll
    for (int q = 0; q < 4; ++q) {
      float4 v = ((const float4*)asrc)[q];
      int base = ((hf << 4) + (q << 2)) * 128 +
                 ((((ra >> 3) ^ ((hf << 2) + q)) << 3) | (ra & 7));
      As[base] = v.x; As[base+128] = v.y; As[base+256] = v.z; As[base+384] = v.w;
    }
    const float* wsrc = W + (size_t)(w0 + wb) * 128 + cp * 16;
    #pragma unroll
    for (int q = 0; q < 4; ++q)
      *(float4*)&Wsb[wb][cp*16 + q*4] = ((const float4*)wsrc)[q];
    __syncthreads();
    #pragma unroll
    for (int k4 = 0; k4 < 8; ++k4) {
      const float* pa = &As[(k4 << 9) + ((rg ^ k4) << 3)];
      #pragma unroll
      for (int kk = 0; kk < 4; ++kk) {
        int w = (k4 << 2) + kk;
        float4 a0 = *(const float4*)(pa + (kk << 7));
        float4 a1 = *(const float4*)(pa + (kk << 7) + 4);
        float4 wv0 = *(const float4*)&Wsb[w][cg*4];
        float4 wv1 = *(const float4*)&Wsb[w][64 + cg*4];
        float av[8] = {a0.x,a0.y,a0.z,a0.w,a1.x,a1.y,a1.z,a1.w};
        float wv[8] = {wv0.x,wv0.y,wv0.z,wv0.w,wv1.x,wv1.y,wv1.z,wv1.w};
        #pragma unroll
        for (int ri = 0; ri < 8; ++ri)
          #pragma unroll
          for (int ci = 0; ci < 8; ++ci)
            acc[ri][ci] = fmaf(av[ri], wv[ci], acc[ri][ci]);
      }
    }
    __syncthreads();
  }
  float blo[4], bhi[4];
  #pragma unroll
  for (int ci = 0; ci < 4; ++ci) {
    blo[ci] = bias ? bias[cg*4 + ci] : 0.f;
    bhi[ci] = bias ? bias[64 + cg*4 + ci] : 0.f;
  }
  if (PAIRMAX) {
    #pragma unroll
    for (int ri = 0; ri < 8; ri += 2) {
      size_t orow = (r0 + rg*8 + ri) >> 1;
      float lo[4], hi[4];
      #pragma unroll
      for (int ci = 0; ci < 4; ++ci) {
        float v0 = acc[ri][ci]   + blo[ci];
        float v1 = acc[ri+1][ci] + blo[ci];
        lo[ci] = fmaxf(fmaxf(v0, v1), 0.f);
        float w0v = acc[ri][ci+4]   + bhi[ci];
        float w1v = acc[ri+1][ci+4] + bhi[ci];
        hi[ci] = fmaxf(fmaxf(w0v, w1v), 0.f);
      }
      *(float4*)&out[orow*128 + cg*4]      = *(float4*)lo;
      *(float4*)&out[orow*128 + 64 + cg*4] = *(float4*)hi;
    }
  } else {
    #pragma unroll
    for (int ri = 0; ri < 8; ++ri) {
      size_t row = r0 + rg*8 + ri;
      float lo[4], hi[4];
      #pragma unroll
      for (int ci = 0; ci < 4; ++ci) {
        float v0 = acc[ri][ci]   + blo[ci];
        float v1 = acc[ri][ci+4] + bhi[ci];
        lo[ci] = RELU ? fmaxf(v0, 0.f) : v0;
        hi[ci] = RELU ? fmaxf(v1, 0.f) : v1;
      }
      *(float4*)&out[row*128 + cg*4]      = *(float4*)lo;
      *(float4*)&out[row*128 + 64 + cg*4] = *(float4*)hi;
    }
  }
}

__global__ __launch_bounds__(256) void pn_gemm128_bias(const float* __restrict__ A,
                                                       const float* __restrict__ W,
                                                       const float* __restrict__ bias,
                                                       float* __restrict__ out) {
  gemm128_core<true, true>(blockIdx.x, A, W, bias, out);
}

__global__ __launch_bounds__(256) void pn_gemm128_uv(const float* __restrict__ A,
                                                     const float* __restrict__ Wb,
                                                     float* __restrict__ U,
                                                     float* __restrict__ V) {
  int which = blockIdx.x >> 9;
  gemm128_core<false, false>(blockIdx.x & 511, A, Wb + (which << 14), nullptr,
                             which ? V : U);
}

// ---------------- row squared norms ----------------
__global__ __launch_bounds__(256) void pn_sqnorm(const float* __restrict__ y,
                                                 float* __restrict__ sq) {
  int r = blockIdx.x * 256 + threadIdx.x;
  const float4* p = (const float4*)(y + (size_t)r * 128);
  float s = 0.f;
  #pragma unroll
  for (int q = 0; q < 32; ++q) {
    float4 v = p[q];
    s += v.x*v.x + v.y*v.y + v.z*v.z + v.w*v.w;
  }
  sq[r] = s;
}

// ---------------- split y -> bf16 hi/lo ----------------
__global__ __launch_bounds__(256) void pn_split(const float* __restrict__ y,
                                                unsigned short* __restrict__ yh,
                                                unsigned short* __restrict__ yl) {
  int gid = blockIdx.x * 256 + threadIdx.x;
  float4 v = ((const float4*)y)[gid];
  ushort4 h, l;
  h.x = f2bf(v.x); l.x = f2bf(v.x - __uint_as_float((unsigned)h.x << 16));
  h.y = f2bf(v.y); l.y = f2bf(v.y - __uint_as_float((unsigned)h.y << 16));
  h.z = f2bf(v.z); l.z = f2bf(v.z - __uint_as_float((unsigned)h.z << 16));
  h.w = f2bf(v.w); l.w = f2bf(v.w - __uint_as_float((unsigned)h.w << 16));
  ((ushort4*)yh)[gid] = h;
  ((ushort4*)yl)[gid] = l;
}

// ---------------- KNN-128 MFMA filter: approx top-3 per row ----------------
__global__ __launch_bounds__(256) void pn_knn_mfma(const unsigned short* __restrict__ Yh,
                                                   const unsigned short* __restrict__ Yl,
                                                   const float* __restrict__ sqn,
                                                   int4* __restrict__ cand) {
  __shared__ __align__(16) unsigned short Ah[128*72];
  __shared__ __align__(16) unsigned short Al[128*72];
  __shared__ __align__(16) unsigned short Bh[128*72];
  __shared__ __align__(16) unsigned short Bl[128*72];
  __shared__ float sqs[1024];
  int t = threadIdx.x;
  int b  = blockIdx.x >> 3;
  int it = blockIdx.x & 7;
  int i0 = it * 128;
  int lane = t & 63, wave = t >> 6;
  int quad = lane >> 4, l16 = lane & 15;
  #pragma unroll
  for (int s = 0; s < 4; ++s) sqs[t + 256*s] = sqn[b*1024 + t + 256*s];

  float D1[8], D2[8], D3[8]; int J1[8], J2[8], J3[8];
  #pragma unroll
  for (int r = 0; r < 8; ++r) {
    D1[r] = FLT_MAX; D2[r] = FLT_MAX; D3[r] = FLT_MAX;
    J1[r] = 0x7fffffff; J2[r] = 0x7fffffff; J3[r] = 0x7fffffff;
  }

  int sr = t >> 1, shf = t & 1;

  #pragma unroll 1
  for (int jc = 0; jc < 8; ++jc) {
    f32x4 acc[2][8];
    #pragma unroll
    for (int s = 0; s < 2; ++s)
      #pragma unroll
      for (int js = 0; js < 8; ++js)
        acc[s][js] = (f32x4){0.f, 0.f, 0.f, 0.f};

    #pragma unroll 1
    for (int kc = 0; kc < 2; ++kc) {
      __syncthreads();
      {
        size_t ga = (size_t)(b*1024 + i0 + sr) * 128 + kc*64 + shf*32;
        size_t gb = (size_t)(b*1024 + jc*128 + sr) * 128 + kc*64 + shf*32;
        const uint4* sAh = (const uint4*)&Yh[ga];
        const uint4* sAl = (const uint4*)&Yl[ga];
        const uint4* sBh = (const uint4*)&Yh[gb];
        const uint4* sBl = (const uint4*)&Yl[gb];
        uint4* dAh = (uint4*)&Ah[sr*72 + shf*32];
        uint4* dAl = (uint4*)&Al[sr*72 + shf*32];
        uint4* dBh = (uint4*)&Bh[sr*72 + shf*32];
        uint4* dBl = (uint4*)&Bl[sr*72 + shf*32];
        #pragma unroll
        for (int q = 0; q < 4; ++q) {
          dAh[q] = sAh[q]; dAl[q] = sAl[q];
          dBh[q] = sBh[q]; dBl[q] = sBl[q];
        }
      }
      __syncthreads();
      #pragma unroll
      for (int ks = 0; ks < 2; ++ks) {
        int ko = ks*32 + quad*8;
        short8 ah0 = *(const short8*)&Ah[(wave*32 + l16)*72 + ko];
        short8 ah1 = *(const short8*)&Ah[(wave*32 + 16 + l16)*72 + ko];
        short8 al0 = *(const short8*)&Al[(wave*32 + l16)*72 + ko];
        short8 al1 = *(const short8*)&Al[(wave*32 + 16 + l16)*72 + ko];
        #pragma unroll
        for (int js = 0; js < 8; ++js) {
          short8 bh = *(const short8*)&Bh[(js*16 + l16)*72 + ko];
          short8 bl = *(const short8*)&Bl[(js*16 + l16)*72 + ko];
          acc[0][js] = __builtin_amdgcn_mfma_f32_16x16x32_bf16(ah0, bh, acc[0][js], 0, 0, 0);
          acc[0][js] = __builtin_amdgcn_mfma_f32_16x16x32_bf16(ah0, bl, acc[0][js], 0, 0, 0);
          acc[0][js] = __builtin_amdgcn_mfma_f32_16x16x32_bf16(al0, bh, acc[0][js], 0, 0, 0);
          acc[0][js] = __builtin_amdgcn_mfma_f32_16x16x32_bf16(al0, bl, acc[0][js], 0, 0, 0);
          acc[1][js] = __builtin_amdgcn_mfma_f32_16x16x32_bf16(ah1, bh, acc[1][js], 0, 0, 0);
          acc[1][js] = __builtin_amdgcn_mfma_f32_16x16x32_bf16(ah1, bl, acc[1][js], 0, 0, 0);
          acc[1][js] = __builtin_amdgcn_mfma_f32_16x16x32_bf16(al1, bh, acc[1][js], 0, 0, 0);
          acc[1][js] = __builtin_amdgcn_mfma_f32_16x16x32_bf16(al1, bl, acc[1][js], 0, 0, 0);
        }
      }
    }
    #pragma unroll
    for (int js = 0; js < 8; ++js) {
      int jg = jc*128 + js*16 + l16;
      float sj = sqs[jg];
      #pragma unroll
      for (int s = 0; s < 2; ++s)
        #pragma unroll
        for (int r = 0; r < 4; ++r) {
          float dd = fmaf(-2.f, acc[s][js][r], sj);
          int id8 = s*4 + r;
          top3_update(D1[id8], J1[id8], D2[id8], J2[id8], D3[id8], J3[id8], dd, jg);
        }
    }
  }

  #pragma unroll
  for (int id8 = 0; id8 < 8; ++id8) {
    #pragma unroll
    for (int m = 1; m < 16; m <<= 1) {
      float o1 = __shfl_xor(D1[id8], m, 64); int p1 = __shfl_xor(J1[id8], m, 64);
      float o2 = __shfl_xor(D2[id8], m, 64); int p2 = __shfl_xor(J2[id8], m, 64);
      float o3 = __shfl_xor(D3[id8], m, 64); int p3 = __shfl_xor(J3[id8], m, 64);
      top3_update(D1[id8], J1[id8], D2[id8], J2[id8], D3[id8], J3[id8], o1, p1);
      top3_update(D1[id8], J1[id8], D2[id8], J2[id8], D3[id8], J3[id8], o2, p2);
      top3_update(D1[id8], J1[id8], D2[id8], J2[id8], D3[id8], J3[id8], o3, p3);
    }
    if (l16 == 0) {
      int s = id8 >> 2, r = id8 & 3;
      int row = b*1024 + i0 + wave*32 + s*16 + quad*4 + r;
      cand[row] = make_int4(J1[id8], J2[id8], J3[id8], 0x7fffffff);
    }
  }
}

// ---------------- exact rescore of 3 candidates ----------------
__global__ __launch_bounds__(256) void pn_knn_rescore(const float* __restrict__ Y,
                                                      const float* __restrict__ sqn,
                                                      const int4* __restrict__ cand,
                                                      int* __restrict__ idx) {
  int gid = blockIdx.x * 256 + threadIdx.x;
  int row = gid >> 2, c = gid & 3;
  int base = (row >> 10) << 10;
  int4 cd = cand[row];
  int cj = (c == 0) ? cd.x : (c == 1) ? cd.y : cd.z;
  const float4* yi = (const float4*)&Y[(size_t)row * 128];
  const float4* yj = (const float4*)&Y[(size_t)(base + cj) * 128];
  float acc = 0.f;
  #pragma unroll 8
  for (int q = 0; q < 32; ++q) {
    float4 a = yi[q], bq = yj[q];
    acc = fmaf(a.x, bq.x, acc);
    acc = fmaf(a.y, bq.y, acc);
    acc = fmaf(a.z, bq.z, acc);
    acc = fmaf(a.w, bq.w, acc);
  }
  float dd = sqn[row] + sqn[base + cj] - 2.0f * acc;
  int jv = cj;
  if (c == 3) { dd = FLT_MAX; jv = 0x7fffffff; }
  float d1 = dd, d2 = FLT_MAX; int j1 = jv, j2 = 0x7fffffff;
  top2_merge_xor(d1, j1, d2, j2, 1);
  top2_merge_xor(d1, j1, d2, j2, 2);
  if (c == 0) {
    idx[row*2+0] = j1;
    idx[row*2+1] = j2;
  }
}

// ---------------- edge epilogue ----------------
__global__ __launch_bounds__(256) void pn_edge_max(const float* __restrict__ U,
                                                   const float* __restrict__ V,
                                                   const int* __restrict__ idx,
                                                   const float* __restrict__ bias,
                                                   float* __restrict__ y) {
  int gid = blockIdx.x * 256 + threadIdx.x;
  int i = gid >> 5, c4 = (gid & 31) << 2;
  int base = (i >> 10) << 10;
  int j0 = idx[i*2+0], j1 = idx[i*2+1];
  float4 u  = *(const float4*)&U[(size_t)i*128 + c4];
  float4 vi = *(const float4*)&V[(size_t)i*128 + c4];
  float4 v0 = *(const float4*)&V[(size_t)(base + j0)*128 + c4];
  float4 v1 = *(const float4*)&V[(size_t)(base + j1)*128 + c4];
  float4 bb = *(const float4*)&bias[c4];
  float4 o;
  o.x = fmaxf(fmaxf(u.x + v0.x - vi.x + bb.x, u.x + v1.x - vi.x + bb.x), 0.f);
  o.y = fmaxf(fmaxf(u.y + v0.y - vi.y + bb.y, u.y + v1.y - vi.y + bb.y), 0.f);
  o.z = fmaxf(fmaxf(u.z + v0.z - vi.z + bb.z, u.z + v1.z - vi.z + bb.z), 0.f);
  o.w = fmaxf(fmaxf(u.w + v0.w - vi.w + bb.w, u.w + v1.w - vi.w + bb.w), 0.f);
  *(float4*)&y[(size_t)i*128 + c4] = o;
}

// ---------------- pooling: 4 n-chunks + combine ----------------
__global__ __launch_bounds__(384) void pn_pool1(const float* __restrict__ y1,
                                                const float* __restrict__ y2,
                                                const float* __restrict__ y3,
                                                float* __restrict__ pp) {
  int b = blockIdx.x >> 2, ch = blockIdx.x & 3, c = threadIdx.x;
  const float* src = (c < 128) ? (y1 + (size_t)b * 131072 + c)
                   : (c < 256) ? (y2 + (size_t)b * 131072 + (c - 128))
                               : (y3 + (size_t)b * 131072 + (c - 256));
  src += (size_t)ch * 256 * 128;
  float s = 0.f, mx = -FLT_MAX;
  for (int n = 0; n < 256; ++n) {
    float v = src[(size_t)n * 128];
    s += v; mx = fmaxf(mx, v);
  }
  pp[(size_t)(b*4 + ch) * 768 + c] = s;
  pp[(size_t)(b*4 + ch) * 768 + 384 + c] = mx;
}

__global__ __launch_bounds__(384) void pn_pool2(const float* __restrict__ pp,
                                                float* __restrict__ g) {
  int b = blockIdx.x, c = threadIdx.x;
  float s = 0.f, mx = -FLT_MAX;
  #pragma unroll
  for (int ch = 0; ch < 4; ++ch) {
    s += pp[(size_t)(b*4 + ch) * 768 + c];
    mx = fmaxf(mx, pp[(size_t)(b*4 + ch) * 768 + 384 + c]);
  }
  g[b*768 + c] = s * (1.0f / 1024.0f);
  g[b*768 + 384 + c] = mx;
}

// ---------------- batchnorm ----------------
__global__ __launch_bounds__(256) void pn_bn(const float* __restrict__ g,
                                             const float* __restrict__ gamma,
                                             const float* __restrict__ beta,
                                             float* __restrict__ out) {
  int c = blockIdx.x * 256 + threadIdx.x;
  float mu = 0.f;
  for (int b = 0; b < 64; ++b) mu += g[b*768 + c];
  mu *= (1.0f / 64.0f);
  float var = 0.f;
  for (int b = 0; b < 64; ++b) { float d = g[b*768 + c] - mu; var += d * d; }
  var *= (1.0f / 64.0f);
  float sc = (1.0f / sqrtf(var + 1e-5f)) * gamma[c];
  float sh = beta[c];
  for (int b = 0; b < 64; ++b) out[b*768 + c] = (g[b*768 + c] - mu) * sc + sh;
}

// ---------------- dense 768->768 (+leaky), 4-acc ILP ----------------
__global__ __launch_bounds__(256) void pn_dense(const float* __restrict__ h,
                                                const float* __restrict__ W,
                                                const float* __restrict__ bias,
                                                float* __restrict__ out) {
  int b = blockIdx.x / 3;
  int c = (blockIdx.x % 3) * 256 + threadIdx.x;
  const float* hb = h + (size_t)b * 768;
  float a0 = bias[c], a1 = 0.f, a2 = 0.f, a3 = 0.f;
  for (int w = 0; w < 768; w += 4) {
    a0 = fmaf(hb[w+0], W[(size_t)(w+0)*768 + c], a0);
    a1 = fmaf(hb[w+1], W[(size_t)(w+1)*768 + c], a1);
    a2 = fmaf(hb[w+2], W[(size_t)(w+2)*768 + c], a2);
    a3 = fmaf(hb[w+3], W[(size_t)(w+3)*768 + c], a3);
  }
  float acc = (a0 + a1) + (a2 + a3);
  acc = acc > 0.f ? acc : 0.01f * acc;
  out[b*768 + c] = acc;
}

// ---------------- final 768->1 ----------------
__global__ __launch_bounds__(256) void pn_out(const float* __restrict__ h,
                                              const float* __restrict__ ow,
                                              const float* __restrict__ ob,
                                              float* __restrict__ out) {
  int wid = blockIdx.x * 4 + (threadIdx.x >> 6);
  int lane = threadIdx.x & 63;
  const float* hb = h + (size_t)wid * 768;
  float s = 0.f;
  #pragma unroll
  for (int q = 0; q < 12; ++q) {
    int w = q * 64 + lane;
    s = fmaf(hb[w], ow[w], s);
  }
  #pragma unroll
  for (int m = 1; m < 64; m <<= 1) s += __shfl_xor(s, m, 64);
  if (lane == 0) out[wid] = s + ob[0];
}

extern "C" void kernel_launch(void* const* d_in, const int* in_sizes, int n_in,
                              void* d_out, int out_size, void* d_ws, size_t ws_size,
                              hipStream_t stream) {
  (void)in_sizes; (void)n_in; (void)out_size; (void)ws_size;
  const float* x     = (const float*)d_in[0];
  const float* p1w1  = (const float*)d_in[1];
  const float* p1b1  = (const float*)d_in[2];
  const float* p1w2  = (const float*)d_in[3];
  const float* p1b2  = (const float*)d_in[4];
  const float* cw    = (const float*)d_in[5];
  const float* cb    = (const float*)d_in[6];
  const float* bng   = (const float*)d_in[7];
  const float* bnb   = (const float*)d_in[8];
  const float* linw  = (const float*)d_in[9];
  const float* linb  = (const float*)d_in[10];
  const float* outw  = (const float*)d_in[11];
  const float* outb  = (const float*)d_in[12];
  float* outp = (float*)d_out;

  float* ws = (float*)d_ws;
  const size_t YSZ = (size_t)65536 * 128;
  float* y1 = ws;
  float* y2 = y1 + YSZ;
  float* y3 = y2 + YSZ;
  float* U  = y3 + YSZ;
  float* V  = U + YSZ;
  float* h1 = U;                         // conv1 scratch, dead after gemm_bias
  unsigned short* yh = (unsigned short*)U;           // 16 MB
  unsigned short* yl = (unsigned short*)U + YSZ;     // second 16 MB of U region
  int4* cand = (int4*)V;                 // knn5: 8 MB, mfma: 1 MB; dead before V write
  float* sq = V + YSZ;
  int*   idxb = (int*)(sq + 65536);
  float* g  = (float*)(idxb + 131072);
  float* ha = g + 49152;
  float* hb = ha + 49152;
  float* pp = hb + 49152;                // pool partials: 256*768 floats

  // --- conv1 ---
  pn_knn5<<<512, 256, 0, stream>>>(x, cand);
  pn_knn_merge<<<256, 256, 0, stream>>>(cand, 8, idxb);
  pn_conv1_l1<<<4096, 256, 0, stream>>>(x, idxb, p1w1, p1b1, h1);
  pn_gemm128_bias<<<1024, 256, 0, stream>>>(h1, p1w2, p1b2, y1);
  // --- conv2 ---
  pn_sqnorm<<<256, 256, 0, stream>>>(y1, sq);
  pn_split<<<8192, 256, 0, stream>>>(y1, yh, yl);
  pn_knn_mfma<<<512, 256, 0, stream>>>(yh, yl, sq, cand);
  pn_knn_rescore<<<1024, 256, 0, stream>>>(y1, sq, cand, idxb);
  pn_gemm128_uv<<<1024, 256, 0, stream>>>(y1, cw, U, V);
  pn_edge_max<<<8192, 256, 0, stream>>>(U, V, idxb, cb, y2);
  // --- conv3 ---
  pn_sqnorm<<<256, 256, 0, stream>>>(y2, sq);
  pn_split<<<8192, 256, 0, stream>>>(y2, yh, yl);
  pn_knn_mfma<<<512, 256, 0, stream>>>(yh, yl, sq, cand);
  pn_knn_rescore<<<1024, 256, 0, stream>>>(y2, sq, cand, idxb);
  pn_gemm128_uv<<<1024, 256, 0, stream>>>(y2, cw + 32768, U, V);
  pn_edge_max<<<8192, 256, 0, stream>>>(U, V, idxb, cb + 128, y3);
  // --- head ---
  pn_pool1<<<256, 384, 0, stream>>>(y1, y2, y3, pp);
  pn_pool2<<<64, 384, 0, stream>>>(pp, g);
  pn_bn<<<3, 256, 0, stream>>>(g, bng, bnb, ha);
  pn_dense<<<192, 256, 0, stream>>>(ha, linw + 0*589824, linb + 0*768, hb);
  pn_dense<<<192, 256, 0, stream>>>(hb, linw + 1*589824, linb + 1*768, ha);
  pn_dense<<<192, 256, 0, stream>>>(ha, linw + 2*589824, linb + 2*768, hb);
  pn_dense<<<192, 256, 0, stream>>>(hb, linw + 3*589824, linb + 3*768, ha);
  pn_dense<<<192, 256, 0, stream>>>(ha, linw + 4*589824, linb + 4*768, hb);
  pn_out<<<16, 256, 0, stream>>>(hb, outw, outb, outp);
}

// Round 10
// 1053.771 us; speedup vs baseline: 2.1783x; 1.0935x over previous
//
#include <hip/hip_runtime.h>
#include <cfloat>

// PointNet / DGCNN: B=64, N=1024, F=5, W=128, K=2, D2=768
// R10: pn_knn5 spill-proof rewrite. R9's xi[4][5] was demoted to scratch
//      (VGPR=20, 8MB scratch writes, inner-loop fills -> 250us at 15% VALU).
//      Now: 2 rows/thread in NAMED scalars (float4+float), SoA LDS (xs4/xs1),
//      grid 64ev x 8js x 2ih = 1024 blocks (4/CU). Same distance expression,
//      same cand/merge semantics -> same picks. Rest unchanged from R9.

typedef short short8 __attribute__((ext_vector_type(8)));
typedef float f32x4 __attribute__((ext_vector_type(4)));

__device__ __forceinline__ unsigned short f2bf(float f) {
  unsigned u = __float_as_uint(f);
  return (unsigned short)((u + 0x7fffu + ((u >> 16) & 1u)) >> 16);
}

__device__ __forceinline__ void top2_update(float& d1, int& j1, float& d2, int& j2,
                                            float dd, int j) {
  if (dd < d1 || (dd == d1 && j < j1)) { d2 = d1; j2 = j1; d1 = dd; j1 = j; }
  else if (dd < d2 || (dd == d2 && j < j2)) { d2 = dd; j2 = j; }
}

__device__ __forceinline__ void top2_merge_xor(float& d1, int& j1, float& d2, int& j2, int m) {
  float od1 = __shfl_xor(d1, m, 64); int oj1 = __shfl_xor(j1, m, 64);
  float od2 = __shfl_xor(d2, m, 64); int oj2 = __shfl_xor(j2, m, 64);
  bool aw = (d1 < od1) || (d1 == od1 && j1 < oj1);
  float h2d = aw ? d2 : od2;  int h2j = aw ? j2 : oj2;
  float lmd = aw ? od1 : d1;  int lmj = aw ? oj1 : j1;
  float nd1 = aw ? d1 : od1;  int nj1 = aw ? j1 : oj1;
  bool bw = (h2d < lmd) || (h2d == lmd && h2j < lmj);
  d1 = nd1; j1 = nj1;
  d2 = bw ? h2d : lmd; j2 = bw ? h2j : lmj;
}

// approx top-3 (filter only needs to be a superset)
__device__ __forceinline__ void top3_update(float& d1, int& j1, float& d2, int& j2,
                                            float& d3, int& j3, float dd, int j) {
  bool c1 = dd < d1, c2 = dd < d2, c3 = dd < d3;
  float n3 = c2 ? d2 : (c3 ? dd : d3); int m3 = c2 ? j2 : (c3 ? j : j3);
  float n2 = c1 ? d1 : (c2 ? dd : d2); int m2 = c1 ? j1 : (c2 ? j : j2);
  d1 = c1 ? dd : d1; j1 = c1 ? j : j1;
  d2 = n2; j2 = m2; d3 = n3; j3 = m3;
}

// ---------------- KNN on 5-dim x: spill-proof, SoA LDS ----------------
// grid = 64 ev x 8 jslices x 2 ihalves = 1024 blocks (4/CU).
__global__ __launch_bounds__(256) void pn_knn5(const float* __restrict__ x,
                                               int4* __restrict__ cand) {
  __shared__ float  xsa[5120];
  __shared__ __align__(16) float4 xs4[1024];
  __shared__ float  xs1[1024];
  int t = threadIdx.x;
  int b  = blockIdx.x >> 4;
  int js = (blockIdx.x >> 1) & 7;
  int ih = blockIdx.x & 1;
  const float4* xb4 = (const float4*)(x + (size_t)b * 5120);
  #pragma unroll
  for (int s = 0; s < 5; ++s) ((float4*)xsa)[t + 256 * s] = xb4[t + 256 * s];
  __syncthreads();
  #pragma unroll
  for (int q = 0; q < 4; ++q) {
    int r = t + 256*q;
    xs4[r] = make_float4(xsa[r*5], xsa[r*5+1], xsa[r*5+2], xsa[r*5+3]);
    xs1[r] = xsa[r*5+4];
  }
  __syncthreads();

  int ra = ih*512 + t, rb = ra + 256;      // my two rows
  float4 a4 = xs4[ra]; float a1 = xs1[ra];
  float4 b4 = xs4[rb]; float b1 = xs1[rb];

  float da1 = FLT_MAX, da2 = FLT_MAX; int ja1 = 0x7fffffff, ja2 = 0x7fffffff;
  float db1 = FLT_MAX, db2 = FLT_MAX; int jb1 = 0x7fffffff, jb2 = 0x7fffffff;

  int j0 = js * 128;
  #pragma unroll 4
  for (int jj = 0; jj < 128; ++jj) {
    int j = j0 + jj;
    float4 c4 = xs4[j];                    // uniform -> broadcast b128
    float  c1 = xs1[j];
    {
      float f0 = c4.x - a4.x, f1 = c4.y - a4.y, f2 = c4.z - a4.z,
            f3 = c4.w - a4.w, f4 = c1 - a1;
      float dd = f0*f0 + f1*f1 + f2*f2 + f3*f3 + f4*f4;
      top2_update(da1, ja1, da2, ja2, dd, j);
    }
    {
      float f0 = c4.x - b4.x, f1 = c4.y - b4.y, f2 = c4.z - b4.z,
            f3 = c4.w - b4.w, f4 = c1 - b1;
      float dd = f0*f0 + f1*f1 + f2*f2 + f3*f3 + f4*f4;
      top2_update(db1, jb1, db2, jb2, dd, j);
    }
  }
  int rowa = b * 1024 + ra, rowb = b * 1024 + rb;
  cand[(size_t)js * 65536 + rowa] =
    make_int4(__float_as_int(da1), __float_as_int(da2), ja1, ja2);
  cand[(size_t)js * 65536 + rowb] =
    make_int4(__float_as_int(db1), __float_as_int(db2), jb1, jb2);
}

__global__ __launch_bounds__(256) void pn_knn_merge(const int4* __restrict__ cand,
                                                    int nslice,
                                                    int* __restrict__ idx) {
  int r = blockIdx.x * 256 + threadIdx.x;
  float d1 = FLT_MAX, d2 = FLT_MAX; int j1 = 0x7fffffff, j2 = 0x7fffffff;
  for (int s = 0; s < nslice; ++s) {
    int4 c = cand[(size_t)s * 65536 + r];
    top2_update(d1, j1, d2, j2, __int_as_float(c.x), c.z);
    top2_update(d1, j1, d2, j2, __int_as_float(c.y), c.w);
  }
  idx[r*2+0] = j1; idx[r*2+1] = j2;
}

// ---------------- conv1 layer1: 32 rows/block ----------------
__global__ __launch_bounds__(256) void pn_conv1_l1(const float* __restrict__ x,
                                                   const int* __restrict__ idx,
                                                   const float* __restrict__ w1,
                                                   const float* __restrict__ b1,
                                                   float* __restrict__ h1) {
  __shared__ float Ws[1280];
  __shared__ float Bs[128];
  __shared__ float xs[32][10];
  __shared__ int   js[32];
  int t = threadIdx.x;
  int r0 = blockIdx.x * 32;
  for (int s = t; s < 1280; s += 256) Ws[s] = w1[s];
  if (t < 128) Bs[t] = b1[t];
  if (t < 32) {
    int r = r0 + t; int i = r >> 1, k = r & 1;
    js[t] = idx[i*2 + k];
  }
  __syncthreads();
  for (int s = t; s < 320; s += 256) {
    int row = s / 10, f = s % 10;
    int r = r0 + row; int i = r >> 1;
    if (f < 5) xs[row][f] = x[(size_t)i * 5 + f];
    else {
      int jrow = ((i >> 10) << 10) + js[row];
      xs[row][f] = x[(size_t)jrow * 5 + (f - 5)];
    }
  }
  __syncthreads();
  int c = t & 127, rr = t >> 7;
  #pragma unroll
  for (int s = 0; s < 16; ++s) {
    int row = s * 2 + rr;
    float acc = Bs[c];
    #pragma unroll
    for (int f = 0; f < 5; ++f) {
      float a = xs[row][f];
      float d = xs[row][5+f] - a;
      acc = fmaf(a, Ws[f*128 + c], acc);
      acc = fmaf(d, Ws[(5+f)*128 + c], acc);
    }
    h1[(size_t)(r0 + row) * 128 + c] = fmaxf(acc, 0.0f);
  }
}

// ---------------- GEMM core: A[128 rows] @ W[128,128] ----------------
template<bool RELU, bool PAIRMAX>
__device__ __forceinline__ void gemm128_core(int bid, const float* __restrict__ A,
                                             const float* __restrict__ W,
                                             const float* __restrict__ bias,
                                             float* __restrict__ out) {
  __shared__ __align__(16) float As[4096];
  __shared__ __align__(16) float Wsb[32][132];
  int t = threadIdx.x;
  int rg = t >> 4;
  int cg = t & 15;
  float acc[8][8];
  #pragma unroll
  for (int a = 0; a < 8; ++a)
    #pragma unroll
    for (int b = 0; b < 8; ++b) acc[a][b] = 0.f;
  size_t r0 = (size_t)bid * 128;
  int ra = t >> 1, hf = t & 1;
  int wb = t >> 3, cp = t & 7;
  for (int w0 = 0; w0 < 128; w0 += 32) {
    const float* asrc = A + (r0 + ra) * 128 + w0 + hf * 16;
    #pragma unroll
    for (int q = 0; q < 4; ++q) {
      float4 v = ((const float4*)asrc)[q];
      int base = ((hf << 4) + (q << 2)) * 128 +
                 ((((ra >> 3) ^ ((hf << 2) + q)) << 3) | (ra & 7));
      As[base] = v.x; As[base+128] = v.y; As[base+256] = v.z; As[base+384] = v.w;
    }
    const float* wsrc = W + (size_t)(w0 + wb) * 128 + cp * 16;
    #pragma unroll
    for (int q = 0; q < 4; ++q)
      *(float4*)&Wsb[wb][cp*16 + q*4] = ((const float4*)wsrc)[q];
    __syncthreads();
    #pragma unroll
    for (int k4 = 0; k4 < 8; ++k4) {
      const float* pa = &As[(k4 << 9) + ((rg ^ k4) << 3)];
      #pragma unroll
      for (int kk = 0; kk < 4; ++kk) {
        int w = (k4 << 2) + kk;
        float4 a0 = *(const float4*)(pa + (kk << 7));
        float4 a1 = *(const float4*)(pa + (kk << 7) + 4);
        float4 wv0 = *(const float4*)&Wsb[w][cg*4];
        float4 wv1 = *(const float4*)&Wsb[w][64 + cg*4];
        float av[8] = {a0.x,a0.y,a0.z,a0.w,a1.x,a1.y,a1.z,a1.w};
        float wv[8] = {wv0.x,wv0.y,wv0.z,wv0.w,wv1.x,wv1.y,wv1.z,wv1.w};
        #pragma unroll
        for (int ri = 0; ri < 8; ++ri)
          #pragma unroll
          for (int ci = 0; ci < 8; ++ci)
            acc[ri][ci] = fmaf(av[ri], wv[ci], acc[ri][ci]);
      }
    }
    __syncthreads();
  }
  float blo[4], bhi[4];
  #pragma unroll
  for (int ci = 0; ci < 4; ++ci) {
    blo[ci] = bias ? bias[cg*4 + ci] : 0.f;
    bhi[ci] = bias ? bias[64 + cg*4 + ci] : 0.f;
  }
  if (PAIRMAX) {
    #pragma unroll
    for (int ri = 0; ri < 8; ri += 2) {
      size_t orow = (r0 + rg*8 + ri) >> 1;
      float lo[4], hi[4];
      #pragma unroll
      for (int ci = 0; ci < 4; ++ci) {
        float v0 = acc[ri][ci]   + blo[ci];
        float v1 = acc[ri+1][ci] + blo[ci];
        lo[ci] = fmaxf(fmaxf(v0, v1), 0.f);
        float w0v = acc[ri][ci+4]   + bhi[ci];
        float w1v = acc[ri+1][ci+4] + bhi[ci];
        hi[ci] = fmaxf(fmaxf(w0v, w1v), 0.f);
      }
      *(float4*)&out[orow*128 + cg*4]      = *(float4*)lo;
      *(float4*)&out[orow*128 + 64 + cg*4] = *(float4*)hi;
    }
  } else {
    #pragma unroll
    for (int ri = 0; ri < 8; ++ri) {
      size_t row = r0 + rg*8 + ri;
      float lo[4], hi[4];
      #pragma unroll
      for (int ci = 0; ci < 4; ++ci) {
        float v0 = acc[ri][ci]   + blo[ci];
        float v1 = acc[ri][ci+4] + bhi[ci];
        lo[ci] = RELU ? fmaxf(v0, 0.f) : v0;
        hi[ci] = RELU ? fmaxf(v1, 0.f) : v1;
      }
      *(float4*)&out[row*128 + cg*4]      = *(float4*)lo;
      *(float4*)&out[row*128 + 64 + cg*4] = *(float4*)hi;
    }
  }
}

__global__ __launch_bounds__(256) void pn_gemm128_bias(const float* __restrict__ A,
                                                       const float* __restrict__ W,
                                                       const float* __restrict__ bias,
                                                       float* __restrict__ out) {
  gemm128_core<true, true>(blockIdx.x, A, W, bias, out);
}

__global__ __launch_bounds__(256) void pn_gemm128_uv(const float* __restrict__ A,
                                                     const float* __restrict__ Wb,
                                                     float* __restrict__ U,
                                                     float* __restrict__ V) {
  int which = blockIdx.x >> 9;
  gemm128_core<false, false>(blockIdx.x & 511, A, Wb + (which << 14), nullptr,
                             which ? V : U);
}

// ---------------- row squared norms ----------------
__global__ __launch_bounds__(256) void pn_sqnorm(const float* __restrict__ y,
                                                 float* __restrict__ sq) {
  int r = blockIdx.x * 256 + threadIdx.x;
  const float4* p = (const float4*)(y + (size_t)r * 128);
  float s = 0.f;
  #pragma unroll
  for (int q = 0; q < 32; ++q) {
    float4 v = p[q];
    s += v.x*v.x + v.y*v.y + v.z*v.z + v.w*v.w;
  }
  sq[r] = s;
}

// ---------------- split y -> bf16 hi/lo ----------------
__global__ __launch_bounds__(256) void pn_split(const float* __restrict__ y,
                                                unsigned short* __restrict__ yh,
                                                unsigned short* __restrict__ yl) {
  int gid = blockIdx.x * 256 + threadIdx.x;
  float4 v = ((const float4*)y)[gid];
  ushort4 h, l;
  h.x = f2bf(v.x); l.x = f2bf(v.x - __uint_as_float((unsigned)h.x << 16));
  h.y = f2bf(v.y); l.y = f2bf(v.y - __uint_as_float((unsigned)h.y << 16));
  h.z = f2bf(v.z); l.z = f2bf(v.z - __uint_as_float((unsigned)h.z << 16));
  h.w = f2bf(v.w); l.w = f2bf(v.w - __uint_as_float((unsigned)h.w << 16));
  ((ushort4*)yh)[gid] = h;
  ((ushort4*)yl)[gid] = l;
}

// ---------------- KNN-128 MFMA filter: approx top-3 per row ----------------
__global__ __launch_bounds__(256) void pn_knn_mfma(const unsigned short* __restrict__ Yh,
                                                   const unsigned short* __restrict__ Yl,
                                                   const float* __restrict__ sqn,
                                                   int4* __restrict__ cand) {
  __shared__ __align__(16) unsigned short Ah[128*72];
  __shared__ __align__(16) unsigned short Al[128*72];
  __shared__ __align__(16) unsigned short Bh[128*72];
  __shared__ __align__(16) unsigned short Bl[128*72];
  __shared__ float sqs[1024];
  int t = threadIdx.x;
  int b  = blockIdx.x >> 3;
  int it = blockIdx.x & 7;
  int i0 = it * 128;
  int lane = t & 63, wave = t >> 6;
  int quad = lane >> 4, l16 = lane & 15;
  #pragma unroll
  for (int s = 0; s < 4; ++s) sqs[t + 256*s] = sqn[b*1024 + t + 256*s];

  float D1[8], D2[8], D3[8]; int J1[8], J2[8], J3[8];
  #pragma unroll
  for (int r = 0; r < 8; ++r) {
    D1[r] = FLT_MAX; D2[r] = FLT_MAX; D3[r] = FLT_MAX;
    J1[r] = 0x7fffffff; J2[r] = 0x7fffffff; J3[r] = 0x7fffffff;
  }

  int sr = t >> 1, shf = t & 1;

  #pragma unroll 1
  for (int jc = 0; jc < 8; ++jc) {
    f32x4 acc[2][8];
    #pragma unroll
    for (int s = 0; s < 2; ++s)
      #pragma unroll
      for (int js = 0; js < 8; ++js)
        acc[s][js] = (f32x4){0.f, 0.f, 0.f, 0.f};

    #pragma unroll 1
    for (int kc = 0; kc < 2; ++kc) {
      __syncthreads();
      {
        size_t ga = (size_t)(b*1024 + i0 + sr) * 128 + kc*64 + shf*32;
        size_t gb = (size_t)(b*1024 + jc*128 + sr) * 128 + kc*64 + shf*32;
        const uint4* sAh = (const uint4*)&Yh[ga];
        const uint4* sAl = (const uint4*)&Yl[ga];
        const uint4* sBh = (const uint4*)&Yh[gb];
        const uint4* sBl = (const uint4*)&Yl[gb];
        uint4* dAh = (uint4*)&Ah[sr*72 + shf*32];
        uint4* dAl = (uint4*)&Al[sr*72 + shf*32];
        uint4* dBh = (uint4*)&Bh[sr*72 + shf*32];
        uint4* dBl = (uint4*)&Bl[sr*72 + shf*32];
        #pragma unroll
        for (int q = 0; q < 4; ++q) {
          dAh[q] = sAh[q]; dAl[q] = sAl[q];
          dBh[q] = sBh[q]; dBl[q] = sBl[q];
        }
      }
      __syncthreads();
      #pragma unroll
      for (int ks = 0; ks < 2; ++ks) {
        int ko = ks*32 + quad*8;
        short8 ah0 = *(const short8*)&Ah[(wave*32 + l16)*72 + ko];
        short8 ah1 = *(const short8*)&Ah[(wave*32 + 16 + l16)*72 + ko];
        short8 al0 = *(const short8*)&Al[(wave*32 + l16)*72 + ko];
        short8 al1 = *(const short8*)&Al[(wave*32 + 16 + l16)*72 + ko];
        #pragma unroll
        for (int js = 0; js < 8; ++js) {
          short8 bh = *(const short8*)&Bh[(js*16 + l16)*72 + ko];
          short8 bl = *(const short8*)&Bl[(js*16 + l16)*72 + ko];
          acc[0][js] = __builtin_amdgcn_mfma_f32_16x16x32_bf16(ah0, bh, acc[0][js], 0, 0, 0);
          acc[0][js] = __builtin_amdgcn_mfma_f32_16x16x32_bf16(ah0, bl, acc[0][js], 0, 0, 0);
          acc[0][js] = __builtin_amdgcn_mfma_f32_16x16x32_bf16(al0, bh, acc[0][js], 0, 0, 0);
          acc[0][js] = __builtin_amdgcn_mfma_f32_16x16x32_bf16(al0, bl, acc[0][js], 0, 0, 0);
          acc[1][js] = __builtin_amdgcn_mfma_f32_16x16x32_bf16(ah1, bh, acc[1][js], 0, 0, 0);
          acc[1][js] = __builtin_amdgcn_mfma_f32_16x16x32_bf16(ah1, bl, acc[1][js], 0, 0, 0);
          acc[1][js] = __builtin_amdgcn_mfma_f32_16x16x32_bf16(al1, bh, acc[1][js], 0, 0, 0);
          acc[1][js] = __builtin_amdgcn_mfma_f32_16x16x32_bf16(al1, bl, acc[1][js], 0, 0, 0);
        }
      }
    }
    #pragma unroll
    for (int js = 0; js < 8; ++js) {
      int jg = jc*128 + js*16 + l16;
      float sj = sqs[jg];
      #pragma unroll
      for (int s = 0; s < 2; ++s)
        #pragma unroll
        for (int r = 0; r < 4; ++r) {
          float dd = fmaf(-2.f, acc[s][js][r], sj);
          int id8 = s*4 + r;
          top3_update(D1[id8], J1[id8], D2[id8], J2[id8], D3[id8], J3[id8], dd, jg);
        }
    }
  }

  #pragma unroll
  for (int id8 = 0; id8 < 8; ++id8) {
    #pragma unroll
    for (int m = 1; m < 16; m <<= 1) {
      float o1 = __shfl_xor(D1[id8], m, 64); int p1 = __shfl_xor(J1[id8], m, 64);
      float o2 = __shfl_xor(D2[id8], m, 64); int p2 = __shfl_xor(J2[id8], m, 64);
      float o3 = __shfl_xor(D3[id8], m, 64); int p3 = __shfl_xor(J3[id8], m, 64);
      top3_update(D1[id8], J1[id8], D2[id8], J2[id8], D3[id8], J3[id8], o1, p1);
      top3_update(D1[id8], J1[id8], D2[id8], J2[id8], D3[id8], J3[id8], o2, p2);
      top3_update(D1[id8], J1[id8], D2[id8], J2[id8], D3[id8], J3[id8], o3, p3);
    }
    if (l16 == 0) {
      int s = id8 >> 2, r = id8 & 3;
      int row = b*1024 + i0 + wave*32 + s*16 + quad*4 + r;
      cand[row] = make_int4(J1[id8], J2[id8], J3[id8], 0x7fffffff);
    }
  }
}

// ---------------- exact rescore of 3 candidates ----------------
__global__ __launch_bounds__(256) void pn_knn_rescore(const float* __restrict__ Y,
                                                      const float* __restrict__ sqn,
                                                      const int4* __restrict__ cand,
                                                      int* __restrict__ idx) {
  int gid = blockIdx.x * 256 + threadIdx.x;
  int row = gid >> 2, c = gid & 3;
  int base = (row >> 10) << 10;
  int4 cd = cand[row];
  int cj = (c == 0) ? cd.x : (c == 1) ? cd.y : cd.z;
  const float4* yi = (const float4*)&Y[(size_t)row * 128];
  const float4* yj = (const float4*)&Y[(size_t)(base + cj) * 128];
  float acc = 0.f;
  #pragma unroll 8
  for (int q = 0; q < 32; ++q) {
    float4 a = yi[q], bq = yj[q];
    acc = fmaf(a.x, bq.x, acc);
    acc = fmaf(a.y, bq.y, acc);
    acc = fmaf(a.z, bq.z, acc);
    acc = fmaf(a.w, bq.w, acc);
  }
  float dd = sqn[row] + sqn[base + cj] - 2.0f * acc;
  int jv = cj;
  if (c == 3) { dd = FLT_MAX; jv = 0x7fffffff; }
  float d1 = dd, d2 = FLT_MAX; int j1 = jv, j2 = 0x7fffffff;
  top2_merge_xor(d1, j1, d2, j2, 1);
  top2_merge_xor(d1, j1, d2, j2, 2);
  if (c == 0) {
    idx[row*2+0] = j1;
    idx[row*2+1] = j2;
  }
}

// ---------------- edge epilogue ----------------
__global__ __launch_bounds__(256) void pn_edge_max(const float* __restrict__ U,
                                                   const float* __restrict__ V,
                                                   const int* __restrict__ idx,
                                                   const float* __restrict__ bias,
                                                   float* __restrict__ y) {
  int gid = blockIdx.x * 256 + threadIdx.x;
  int i = gid >> 5, c4 = (gid & 31) << 2;
  int base = (i >> 10) << 10;
  int j0 = idx[i*2+0], j1 = idx[i*2+1];
  float4 u  = *(const float4*)&U[(size_t)i*128 + c4];
  float4 vi = *(const float4*)&V[(size_t)i*128 + c4];
  float4 v0 = *(const float4*)&V[(size_t)(base + j0)*128 + c4];
  float4 v1 = *(const float4*)&V[(size_t)(base + j1)*128 + c4];
  float4 bb = *(const float4*)&bias[c4];
  float4 o;
  o.x = fmaxf(fmaxf(u.x + v0.x - vi.x + bb.x, u.x + v1.x - vi.x + bb.x), 0.f);
  o.y = fmaxf(fmaxf(u.y + v0.y - vi.y + bb.y, u.y + v1.y - vi.y + bb.y), 0.f);
  o.z = fmaxf(fmaxf(u.z + v0.z - vi.z + bb.z, u.z + v1.z - vi.z + bb.z), 0.f);
  o.w = fmaxf(fmaxf(u.w + v0.w - vi.w + bb.w, u.w + v1.w - vi.w + bb.w), 0.f);
  *(float4*)&y[(size_t)i*128 + c4] = o;
}

// ---------------- pooling: 4 n-chunks + combine ----------------
__global__ __launch_bounds__(384) void pn_pool1(const float* __restrict__ y1,
                                                const float* __restrict__ y2,
                                                const float* __restrict__ y3,
                                                float* __restrict__ pp) {
  int b = blockIdx.x >> 2, ch = blockIdx.x & 3, c = threadIdx.x;
  const float* src = (c < 128) ? (y1 + (size_t)b * 131072 + c)
                   : (c < 256) ? (y2 + (size_t)b * 131072 + (c - 128))
                               : (y3 + (size_t)b * 131072 + (c - 256));
  src += (size_t)ch * 256 * 128;
  float s = 0.f, mx = -FLT_MAX;
  for (int n = 0; n < 256; ++n) {
    float v = src[(size_t)n * 128];
    s += v; mx = fmaxf(mx, v);
  }
  pp[(size_t)(b*4 + ch) * 768 + c] = s;
  pp[(size_t)(b*4 + ch) * 768 + 384 + c] = mx;
}

__global__ __launch_bounds__(384) void pn_pool2(const float* __restrict__ pp,
                                                float* __restrict__ g) {
  int b = blockIdx.x, c = threadIdx.x;
  float s = 0.f, mx = -FLT_MAX;
  #pragma unroll
  for (int ch = 0; ch < 4; ++ch) {
    s += pp[(size_t)(b*4 + ch) * 768 + c];
    mx = fmaxf(mx, pp[(size_t)(b*4 + ch) * 768 + 384 + c]);
  }
  g[b*768 + c] = s * (1.0f / 1024.0f);
  g[b*768 + 384 + c] = mx;
}

// ---------------- batchnorm ----------------
__global__ __launch_bounds__(256) void pn_bn(const float* __restrict__ g,
                                             const float* __restrict__ gamma,
                                             const float* __restrict__ beta,
                                             float* __restrict__ out) {
  int c = blockIdx.x * 256 + threadIdx.x;
  float mu = 0.f;
  for (int b = 0; b < 64; ++b) mu += g[b*768 + c];
  mu *= (1.0f / 64.0f);
  float var = 0.f;
  for (int b = 0; b < 64; ++b) { float d = g[b*768 + c] - mu; var += d * d; }
  var *= (1.0f / 64.0f);
  float sc = (1.0f / sqrtf(var + 1e-5f)) * gamma[c];
  float sh = beta[c];
  for (int b = 0; b < 64; ++b) out[b*768 + c] = (g[b*768 + c] - mu) * sc + sh;
}

// ---------------- dense 768->768 (+leaky), 4-acc ILP ----------------
__global__ __launch_bounds__(256) void pn_dense(const float* __restrict__ h,
                                                const float* __restrict__ W,
                                                const float* __restrict__ bias,
                                                float* __restrict__ out) {
  int b = blockIdx.x / 3;
  int c = (blockIdx.x % 3) * 256 + threadIdx.x;
  const float* hb = h + (size_t)b * 768;
  float a0 = bias[c], a1 = 0.f, a2 = 0.f, a3 = 0.f;
  for (int w = 0; w < 768; w += 4) {
    a0 = fmaf(hb[w+0], W[(size_t)(w+0)*768 + c], a0);
    a1 = fmaf(hb[w+1], W[(size_t)(w+1)*768 + c], a1);
    a2 = fmaf(hb[w+2], W[(size_t)(w+2)*768 + c], a2);
    a3 = fmaf(hb[w+3], W[(size_t)(w+3)*768 + c], a3);
  }
  float acc = (a0 + a1) + (a2 + a3);
  acc = acc > 0.f ? acc : 0.01f * acc;
  out[b*768 + c] = acc;
}

// ---------------- final 768->1 ----------------
__global__ __launch_bounds__(256) void pn_out(const float* __restrict__ h,
                                              const float* __restrict__ ow,
                                              const float* __restrict__ ob,
                                              float* __restrict__ out) {
  int wid = blockIdx.x * 4 + (threadIdx.x >> 6);
  int lane = threadIdx.x & 63;
  const float* hb = h + (size_t)wid * 768;
  float s = 0.f;
  #pragma unroll
  for (int q = 0; q < 12; ++q) {
    int w = q * 64 + lane;
    s = fmaf(hb[w], ow[w], s);
  }
  #pragma unroll
  for (int m = 1; m < 64; m <<= 1) s += __shfl_xor(s, m, 64);
  if (lane == 0) out[wid] = s + ob[0];
}

extern "C" void kernel_launch(void* const* d_in, const int* in_sizes, int n_in,
                              void* d_out, int out_size, void* d_ws, size_t ws_size,
                              hipStream_t stream) {
  (void)in_sizes; (void)n_in; (void)out_size; (void)ws_size;
  const float* x     = (const float*)d_in[0];
  const float* p1w1  = (const float*)d_in[1];
  const float* p1b1  = (const float*)d_in[2];
  const float* p1w2  = (const float*)d_in[3];
  const float* p1b2  = (const float*)d_in[4];
  const float* cw    = (const float*)d_in[5];
  const float* cb    = (const float*)d_in[6];
  const float* bng   = (const float*)d_in[7];
  const float* bnb   = (const float*)d_in[8];
  const float* linw  = (const float*)d_in[9];
  const float* linb  = (const float*)d_in[10];
  const float* outw  = (const float*)d_in[11];
  const float* outb  = (const float*)d_in[12];
  float* outp = (float*)d_out;

  float* ws = (float*)d_ws;
  const size_t YSZ = (size_t)65536 * 128;
  float* y1 = ws;
  float* y2 = y1 + YSZ;
  float* y3 = y2 + YSZ;
  float* U  = y3 + YSZ;
  float* V  = U + YSZ;
  float* h1 = U;                         // conv1 scratch, dead after gemm_bias
  unsigned short* yh = (unsigned short*)U;           // 16 MB
  unsigned short* yl = (unsigned short*)U + YSZ;     // second 16 MB of U region
  int4* cand = (int4*)V;                 // knn5: 8 MB, mfma: 1 MB; dead before V write
  float* sq = V + YSZ;
  int*   idxb = (int*)(sq + 65536);
  float* g  = (float*)(idxb + 131072);
  float* ha = g + 49152;
  float* hb = ha + 49152;
  float* pp = hb + 49152;                // pool partials: 256*768 floats

  // --- conv1 ---
  pn_knn5<<<1024, 256, 0, stream>>>(x, cand);
  pn_knn_merge<<<256, 256, 0, stream>>>(cand, 8, idxb);
  pn_conv1_l1<<<4096, 256, 0, stream>>>(x, idxb, p1w1, p1b1, h1);
  pn_gemm128_bias<<<1024, 256, 0, stream>>>(h1, p1w2, p1b2, y1);
  // --- conv2 ---
  pn_sqnorm<<<256, 256, 0, stream>>>(y1, sq);
  pn_split<<<8192, 256, 0, stream>>>(y1, yh, yl);
  pn_knn_mfma<<<512, 256, 0, stream>>>(yh, yl, sq, cand);
  pn_knn_rescore<<<1024, 256, 0, stream>>>(y1, sq, cand, idxb);
  pn_gemm128_uv<<<1024, 256, 0, stream>>>(y1, cw, U, V);
  pn_edge_max<<<8192, 256, 0, stream>>>(U, V, idxb, cb, y2);
  // --- conv3 ---
  pn_sqnorm<<<256, 256, 0, stream>>>(y2, sq);
  pn_split<<<8192, 256, 0, stream>>>(y2, yh, yl);
  pn_knn_mfma<<<512, 256, 0, stream>>>(yh, yl, sq, cand);
  pn_knn_rescore<<<1024, 256, 0, stream>>>(y2, sq, cand, idxb);
  pn_gemm128_uv<<<1024, 256, 0, stream>>>(y2, cw + 32768, U, V);
  pn_edge_max<<<8192, 256, 0, stream>>>(U, V, idxb, cb + 128, y3);
  // --- head ---
  pn_pool1<<<256, 384, 0, stream>>>(y1, y2, y3, pp);
  pn_pool2<<<64, 384, 0, stream>>>(pp, g);
  pn_bn<<<3, 256, 0, stream>>>(g, bng, bnb, ha);
  pn_dense<<<192, 256, 0, stream>>>(ha, linw + 0*589824, linb + 0*768, hb);
  pn_dense<<<192, 256, 0, stream>>>(hb, linw + 1*589824, linb + 1*768, ha);
  pn_dense<<<192, 256, 0, stream>>>(ha, linw + 2*589824, linb + 2*768, hb);
  pn_dense<<<192, 256, 0, stream>>>(hb, linw + 3*589824, linb + 3*768, ha);
  pn_dense<<<192, 256, 0, stream>>>(ha, linw + 4*589824, linb + 4*768, hb);
  pn_out<<<16, 256, 0, stream>>>(hb, outw, outb, outp);
}

// Round 11
// 938.739 us; speedup vs baseline: 2.4452x; 1.1225x over previous
//
#include <hip/hip_runtime.h>
#include <cfloat>

// PointNet / DGCNN: B=64, N=1024, F=5, W=128, K=2, D2=768
// R11: knn5 -> MFMA filter + exact rescore (same proven pattern as the
//      128-dim path from R8). x padded 5->32, bf16 hi/lo 4-pass Gram,
//      approx top-3, exact (xi-xj)^2 rescore with R10's bit-identical fmaf
//      chain -> same picks -> absmax 0.0. Deletes pn_knn5 + pn_knn_merge
//      (R8-R10: scalar top-2 scan never exceeded 26% VALU issue; latency-
//      bound structure). sqnorm kept separate/bit-identical on purpose
//      (reordering sq risks ~1e-5 distance perturbation -> pick flips).

typedef short short8 __attribute__((ext_vector_type(8)));
typedef float f32x4 __attribute__((ext_vector_type(4)));

__device__ __forceinline__ unsigned short f2bf(float f) {
  unsigned u = __float_as_uint(f);
  return (unsigned short)((u + 0x7fffu + ((u >> 16) & 1u)) >> 16);
}

__device__ __forceinline__ void top2_update(float& d1, int& j1, float& d2, int& j2,
                                            float dd, int j) {
  if (dd < d1 || (dd == d1 && j < j1)) { d2 = d1; j2 = j1; d1 = dd; j1 = j; }
  else if (dd < d2 || (dd == d2 && j < j2)) { d2 = dd; j2 = j; }
}

__device__ __forceinline__ void top2_merge_xor(float& d1, int& j1, float& d2, int& j2, int m) {
  float od1 = __shfl_xor(d1, m, 64); int oj1 = __shfl_xor(j1, m, 64);
  float od2 = __shfl_xor(d2, m, 64); int oj2 = __shfl_xor(j2, m, 64);
  bool aw = (d1 < od1) || (d1 == od1 && j1 < oj1);
  float h2d = aw ? d2 : od2;  int h2j = aw ? j2 : oj2;
  float lmd = aw ? od1 : d1;  int lmj = aw ? oj1 : j1;
  float nd1 = aw ? d1 : od1;  int nj1 = aw ? j1 : oj1;
  bool bw = (h2d < lmd) || (h2d == lmd && h2j < lmj);
  d1 = nd1; j1 = nj1;
  d2 = bw ? h2d : lmd; j2 = bw ? h2j : lmj;
}

// approx top-3 (filter only needs to be a superset)
__device__ __forceinline__ void top3_update(float& d1, int& j1, float& d2, int& j2,
                                            float& d3, int& j3, float dd, int j) {
  bool c1 = dd < d1, c2 = dd < d2, c3 = dd < d3;
  float n3 = c2 ? d2 : (c3 ? dd : d3); int m3 = c2 ? j2 : (c3 ? j : j3);
  float n2 = c1 ? d1 : (c2 ? dd : d2); int m2 = c1 ? j1 : (c2 ? j : j2);
  d1 = c1 ? dd : d1; j1 = c1 ? j : j1;
  d2 = n2; j2 = m2; d3 = n3; j3 = m3;
}

// ---------------- split x (5-dim) -> bf16 hi/lo padded to 32, + sq5 ----------
__global__ __launch_bounds__(256) void pn_split5(const float* __restrict__ x,
                                                 unsigned short* __restrict__ xh,
                                                 unsigned short* __restrict__ xl,
                                                 float* __restrict__ sq5) {
  int r = blockIdx.x * 256 + threadIdx.x;   // 65536 rows
  const float* xr = x + (size_t)r * 5;
  float v0 = xr[0], v1 = xr[1], v2 = xr[2], v3 = xr[3], v4 = xr[4];
  unsigned short h0 = f2bf(v0), h1 = f2bf(v1), h2 = f2bf(v2), h3 = f2bf(v3), h4 = f2bf(v4);
  unsigned short l0 = f2bf(v0 - __uint_as_float((unsigned)h0 << 16));
  unsigned short l1 = f2bf(v1 - __uint_as_float((unsigned)h1 << 16));
  unsigned short l2 = f2bf(v2 - __uint_as_float((unsigned)h2 << 16));
  unsigned short l3 = f2bf(v3 - __uint_as_float((unsigned)h3 << 16));
  unsigned short l4 = f2bf(v4 - __uint_as_float((unsigned)h4 << 16));
  uint4 Z = make_uint4(0u, 0u, 0u, 0u);
  uint4 H = make_uint4((unsigned)h0 | ((unsigned)h1 << 16),
                       (unsigned)h2 | ((unsigned)h3 << 16),
                       (unsigned)h4, 0u);
  uint4 L = make_uint4((unsigned)l0 | ((unsigned)l1 << 16),
                       (unsigned)l2 | ((unsigned)l3 << 16),
                       (unsigned)l4, 0u);
  uint4* dh = (uint4*)(xh + (size_t)r * 32);
  uint4* dl = (uint4*)(xl + (size_t)r * 32);
  dh[0] = H; dh[1] = Z; dh[2] = Z; dh[3] = Z;
  dl[0] = L; dl[1] = Z; dl[2] = Z; dl[3] = Z;
  sq5[r] = v0*v0 + v1*v1 + v2*v2 + v3*v3 + v4*v4;
}

// ---------------- KNN-5 MFMA filter: approx top-3 per row (K=32 padded) ------
// grid = 64 ev x 8 itiles = 512 blocks. LDS row stride 40 ushort (80 B):
// 20 dwords mod 32 -> fragment reads <=2-way, 16B aligned.
__global__ __launch_bounds__(256) void pn_knn5_mfma(const unsigned short* __restrict__ Xh,
                                                    const unsigned short* __restrict__ Xl,
                                                    const float* __restrict__ sq5,
                                                    int4* __restrict__ cand) {
  __shared__ __align__(16) unsigned short Ah[128*40];
  __shared__ __align__(16) unsigned short Al[128*40];
  __shared__ __align__(16) unsigned short Bh[128*40];
  __shared__ __align__(16) unsigned short Bl[128*40];
  __shared__ float sqs[1024];
  int t = threadIdx.x;
  int b = blockIdx.x >> 3, it = blockIdx.x & 7, i0 = it * 128;
  int lane = t & 63, wave = t >> 6, quad = lane >> 4, l16 = lane & 15;
  #pragma unroll
  for (int s = 0; s < 4; ++s) sqs[t + 256*s] = sq5[b*1024 + t + 256*s];

  int sr = t >> 1, part = t & 1;
  {
    const uint4* sh = (const uint4*)&Xh[(size_t)(b*1024 + i0 + sr)*32 + part*16];
    const uint4* sl = (const uint4*)&Xl[(size_t)(b*1024 + i0 + sr)*32 + part*16];
    uint4* dh = (uint4*)&Ah[sr*40 + part*16];
    uint4* dl = (uint4*)&Al[sr*40 + part*16];
    dh[0] = sh[0]; dh[1] = sh[1];
    dl[0] = sl[0]; dl[1] = sl[1];
  }
  __syncthreads();
  short8 ah0 = *(const short8*)&Ah[(wave*32 + l16)*40 + quad*8];
  short8 ah1 = *(const short8*)&Ah[(wave*32 + 16 + l16)*40 + quad*8];
  short8 al0 = *(const short8*)&Al[(wave*32 + l16)*40 + quad*8];
  short8 al1 = *(const short8*)&Al[(wave*32 + 16 + l16)*40 + quad*8];

  float D1[8], D2[8], D3[8]; int J1[8], J2[8], J3[8];
  #pragma unroll
  for (int r = 0; r < 8; ++r) {
    D1[r] = FLT_MAX; D2[r] = FLT_MAX; D3[r] = FLT_MAX;
    J1[r] = 0x7fffffff; J2[r] = 0x7fffffff; J3[r] = 0x7fffffff;
  }

  #pragma unroll 1
  for (int jc = 0; jc < 8; ++jc) {
    __syncthreads();
    {
      const uint4* sh = (const uint4*)&Xh[(size_t)(b*1024 + jc*128 + sr)*32 + part*16];
      const uint4* sl = (const uint4*)&Xl[(size_t)(b*1024 + jc*128 + sr)*32 + part*16];
      uint4* dh = (uint4*)&Bh[sr*40 + part*16];
      uint4* dl = (uint4*)&Bl[sr*40 + part*16];
      dh[0] = sh[0]; dh[1] = sh[1];
      dl[0] = sl[0]; dl[1] = sl[1];
    }
    __syncthreads();
    f32x4 acc[2][8];
    #pragma unroll
    for (int s = 0; s < 2; ++s)
      #pragma unroll
      for (int js = 0; js < 8; ++js)
        acc[s][js] = (f32x4){0.f, 0.f, 0.f, 0.f};
    #pragma unroll
    for (int js = 0; js < 8; ++js) {
      short8 bh = *(const short8*)&Bh[(js*16 + l16)*40 + quad*8];
      short8 bl = *(const short8*)&Bl[(js*16 + l16)*40 + quad*8];
      acc[0][js] = __builtin_amdgcn_mfma_f32_16x16x32_bf16(ah0, bh, acc[0][js], 0, 0, 0);
      acc[0][js] = __builtin_amdgcn_mfma_f32_16x16x32_bf16(ah0, bl, acc[0][js], 0, 0, 0);
      acc[0][js] = __builtin_amdgcn_mfma_f32_16x16x32_bf16(al0, bh, acc[0][js], 0, 0, 0);
      acc[0][js] = __builtin_amdgcn_mfma_f32_16x16x32_bf16(al0, bl, acc[0][js], 0, 0, 0);
      acc[1][js] = __builtin_amdgcn_mfma_f32_16x16x32_bf16(ah1, bh, acc[1][js], 0, 0, 0);
      acc[1][js] = __builtin_amdgcn_mfma_f32_16x16x32_bf16(ah1, bl, acc[1][js], 0, 0, 0);
      acc[1][js] = __builtin_amdgcn_mfma_f32_16x16x32_bf16(al1, bh, acc[1][js], 0, 0, 0);
      acc[1][js] = __builtin_amdgcn_mfma_f32_16x16x32_bf16(al1, bl, acc[1][js], 0, 0, 0);
    }
    #pragma unroll
    for (int js = 0; js < 8; ++js) {
      int jg = jc*128 + js*16 + l16;
      float sj = sqs[jg];
      #pragma unroll
      for (int s = 0; s < 2; ++s)
        #pragma unroll
        for (int r = 0; r < 4; ++r) {
          float dd = fmaf(-2.f, acc[s][js][r], sj);
          int id8 = s*4 + r;
          top3_update(D1[id8], J1[id8], D2[id8], J2[id8], D3[id8], J3[id8], dd, jg);
        }
    }
  }

  #pragma unroll
  for (int id8 = 0; id8 < 8; ++id8) {
    #pragma unroll
    for (int m = 1; m < 16; m <<= 1) {
      float o1 = __shfl_xor(D1[id8], m, 64); int p1 = __shfl_xor(J1[id8], m, 64);
      float o2 = __shfl_xor(D2[id8], m, 64); int p2 = __shfl_xor(J2[id8], m, 64);
      float o3 = __shfl_xor(D3[id8], m, 64); int p3 = __shfl_xor(J3[id8], m, 64);
      top3_update(D1[id8], J1[id8], D2[id8], J2[id8], D3[id8], J3[id8], o1, p1);
      top3_update(D1[id8], J1[id8], D2[id8], J2[id8], D3[id8], J3[id8], o2, p2);
      top3_update(D1[id8], J1[id8], D2[id8], J2[id8], D3[id8], J3[id8], o3, p3);
    }
    if (l16 == 0) {
      int s = id8 >> 2, r = id8 & 3;
      int row = b*1024 + i0 + wave*32 + s*16 + quad*4 + r;
      cand[row] = make_int4(J1[id8], J2[id8], J3[id8], 0x7fffffff);
    }
  }
}

// ---------------- exact 5-dim rescore (R10's bit-identical fmaf chain) -------
__global__ __launch_bounds__(256) void pn_knn5_rescore(const float* __restrict__ x,
                                                       const int4* __restrict__ cand,
                                                       int* __restrict__ idx) {
  int r = blockIdx.x * 256 + threadIdx.x;
  int base = (r >> 10) << 10;
  int4 cd = cand[r];
  const float* xi = x + (size_t)r * 5;
  float a0 = xi[0], a1 = xi[1], a2 = xi[2], a3 = xi[3], a4 = xi[4];
  float d1 = FLT_MAX, d2 = FLT_MAX; int j1 = 0x7fffffff, j2 = 0x7fffffff;
  int cs0 = cd.x, cs1 = cd.y, cs2 = cd.z;
  #pragma unroll
  for (int c = 0; c < 3; ++c) {
    int cj = (c == 0) ? cs0 : (c == 1) ? cs1 : cs2;
    const float* xj = x + (size_t)(base + cj) * 5;
    float f0 = xj[0] - a0, f1 = xj[1] - a1, f2 = xj[2] - a2,
          f3 = xj[3] - a3, f4 = xj[4] - a4;
    float dd = f0*f0 + f1*f1 + f2*f2 + f3*f3 + f4*f4;
    top2_update(d1, j1, d2, j2, dd, cj);
  }
  idx[r*2+0] = j1; idx[r*2+1] = j2;
}

// ---------------- conv1 layer1: 32 rows/block ----------------
__global__ __launch_bounds__(256) void pn_conv1_l1(const float* __restrict__ x,
                                                   const int* __restrict__ idx,
                                                   const float* __restrict__ w1,
                                                   const float* __restrict__ b1,
                                                   float* __restrict__ h1) {
  __shared__ float Ws[1280];
  __shared__ float Bs[128];
  __shared__ float xs[32][10];
  __shared__ int   js[32];
  int t = threadIdx.x;
  int r0 = blockIdx.x * 32;
  for (int s = t; s < 1280; s += 256) Ws[s] = w1[s];
  if (t < 128) Bs[t] = b1[t];
  if (t < 32) {
    int r = r0 + t; int i = r >> 1, k = r & 1;
    js[t] = idx[i*2 + k];
  }
  __syncthreads();
  for (int s = t; s < 320; s += 256) {
    int row = s / 10, f = s % 10;
    int r = r0 + row; int i = r >> 1;
    if (f < 5) xs[row][f] = x[(size_t)i * 5 + f];
    else {
      int jrow = ((i >> 10) << 10) + js[row];
      xs[row][f] = x[(size_t)jrow * 5 + (f - 5)];
    }
  }
  __syncthreads();
  int c = t & 127, rr = t >> 7;
  #pragma unroll
  for (int s = 0; s < 16; ++s) {
    int row = s * 2 + rr;
    float acc = Bs[c];
    #pragma unroll
    for (int f = 0; f < 5; ++f) {
      float a = xs[row][f];
      float d = xs[row][5+f] - a;
      acc = fmaf(a, Ws[f*128 + c], acc);
      acc = fmaf(d, Ws[(5+f)*128 + c], acc);
    }
    h1[(size_t)(r0 + row) * 128 + c] = fmaxf(acc, 0.0f);
  }
}

// ---------------- GEMM core: A[128 rows] @ W[128,128] ----------------
template<bool RELU, bool PAIRMAX>
__device__ __forceinline__ void gemm128_core(int bid, const float* __restrict__ A,
                                             const float* __restrict__ W,
                                             const float* __restrict__ bias,
                                             float* __restrict__ out) {
  __shared__ __align__(16) float As[4096];
  __shared__ __align__(16) float Wsb[32][132];
  int t = threadIdx.x;
  int rg = t >> 4;
  int cg = t & 15;
  float acc[8][8];
  #pragma unroll
  for (int a = 0; a < 8; ++a)
    #pragma unroll
    for (int b = 0; b < 8; ++b) acc[a][b] = 0.f;
  size_t r0 = (size_t)bid * 128;
  int ra = t >> 1, hf = t & 1;
  int wb = t >> 3, cp = t & 7;
  for (int w0 = 0; w0 < 128; w0 += 32) {
    const float* asrc = A + (r0 + ra) * 128 + w0 + hf * 16;
    #pragma unroll
    for (int q = 0; q < 4; ++q) {
      float4 v = ((const float4*)asrc)[q];
      int base = ((hf << 4) + (q << 2)) * 128 +
                 ((((ra >> 3) ^ ((hf << 2) + q)) << 3) | (ra & 7));
      As[base] = v.x; As[base+128] = v.y; As[base+256] = v.z; As[base+384] = v.w;
    }
    const float* wsrc = W + (size_t)(w0 + wb) * 128 + cp * 16;
    #pragma unroll
    for (int q = 0; q < 4; ++q)
      *(float4*)&Wsb[wb][cp*16 + q*4] = ((const float4*)wsrc)[q];
    __syncthreads();
    #pragma unroll
    for (int k4 = 0; k4 < 8; ++k4) {
      const float* pa = &As[(k4 << 9) + ((rg ^ k4) << 3)];
      #pragma unroll
      for (int kk = 0; kk < 4; ++kk) {
        int w = (k4 << 2) + kk;
        float4 a0 = *(const float4*)(pa + (kk << 7));
        float4 a1 = *(const float4*)(pa + (kk << 7) + 4);
        float4 wv0 = *(const float4*)&Wsb[w][cg*4];
        float4 wv1 = *(const float4*)&Wsb[w][64 + cg*4];
        float av[8] = {a0.x,a0.y,a0.z,a0.w,a1.x,a1.y,a1.z,a1.w};
        float wv[8] = {wv0.x,wv0.y,wv0.z,wv0.w,wv1.x,wv1.y,wv1.z,wv1.w};
        #pragma unroll
        for (int ri = 0; ri < 8; ++ri)
          #pragma unroll
          for (int ci = 0; ci < 8; ++ci)
            acc[ri][ci] = fmaf(av[ri], wv[ci], acc[ri][ci]);
      }
    }
    __syncthreads();
  }
  float blo[4], bhi[4];
  #pragma unroll
  for (int ci = 0; ci < 4; ++ci) {
    blo[ci] = bias ? bias[cg*4 + ci] : 0.f;
    bhi[ci] = bias ? bias[64 + cg*4 + ci] : 0.f;
  }
  if (PAIRMAX) {
    #pragma unroll
    for (int ri = 0; ri < 8; ri += 2) {
      size_t orow = (r0 + rg*8 + ri) >> 1;
      float lo[4], hi[4];
      #pragma unroll
      for (int ci = 0; ci < 4; ++ci) {
        float v0 = acc[ri][ci]   + blo[ci];
        float v1 = acc[ri+1][ci] + blo[ci];
        lo[ci] = fmaxf(fmaxf(v0, v1), 0.f);
        float w0v = acc[ri][ci+4]   + bhi[ci];
        float w1v = acc[ri+1][ci+4] + bhi[ci];
        hi[ci] = fmaxf(fmaxf(w0v, w1v), 0.f);
      }
      *(float4*)&out[orow*128 + cg*4]      = *(float4*)lo;
      *(float4*)&out[orow*128 + 64 + cg*4] = *(float4*)hi;
    }
  } else {
    #pragma unroll
    for (int ri = 0; ri < 8; ++ri) {
      size_t row = r0 + rg*8 + ri;
      float lo[4], hi[4];
      #pragma unroll
      for (int ci = 0; ci < 4; ++ci) {
        float v0 = acc[ri][ci]   + blo[ci];
        float v1 = acc[ri][ci+4] + bhi[ci];
        lo[ci] = RELU ? fmaxf(v0, 0.f) : v0;
        hi[ci] = RELU ? fmaxf(v1, 0.f) : v1;
      }
      *(float4*)&out[row*128 + cg*4]      = *(float4*)lo;
      *(float4*)&out[row*128 + 64 + cg*4] = *(float4*)hi;
    }
  }
}

__global__ __launch_bounds__(256) void pn_gemm128_bias(const float* __restrict__ A,
                                                       const float* __restrict__ W,
                                                       const float* __restrict__ bias,
                                                       float* __restrict__ out) {
  gemm128_core<true, true>(blockIdx.x, A, W, bias, out);
}

__global__ __launch_bounds__(256) void pn_gemm128_uv(const float* __restrict__ A,
                                                     const float* __restrict__ Wb,
                                                     float* __restrict__ U,
                                                     float* __restrict__ V) {
  int which = blockIdx.x >> 9;
  gemm128_core<false, false>(blockIdx.x & 511, A, Wb + (which << 14), nullptr,
                             which ? V : U);
}

// ---------------- row squared norms (bit-identical to R10) ----------------
__global__ __launch_bounds__(256) void pn_sqnorm(const float* __restrict__ y,
                                                 float* __restrict__ sq) {
  int r = blockIdx.x * 256 + threadIdx.x;
  const float4* p = (const float4*)(y + (size_t)r * 128);
  float s = 0.f;
  #pragma unroll
  for (int q = 0; q < 32; ++q) {
    float4 v = p[q];
    s += v.x*v.x + v.y*v.y + v.z*v.z + v.w*v.w;
  }
  sq[r] = s;
}

// ---------------- split y -> bf16 hi/lo ----------------
__global__ __launch_bounds__(256) void pn_split(const float* __restrict__ y,
                                                unsigned short* __restrict__ yh,
                                                unsigned short* __restrict__ yl) {
  int gid = blockIdx.x * 256 + threadIdx.x;
  float4 v = ((const float4*)y)[gid];
  ushort4 h, l;
  h.x = f2bf(v.x); l.x = f2bf(v.x - __uint_as_float((unsigned)h.x << 16));
  h.y = f2bf(v.y); l.y = f2bf(v.y - __uint_as_float((unsigned)h.y << 16));
  h.z = f2bf(v.z); l.z = f2bf(v.z - __uint_as_float((unsigned)h.z << 16));
  h.w = f2bf(v.w); l.w = f2bf(v.w - __uint_as_float((unsigned)h.w << 16));
  ((ushort4*)yh)[gid] = h;
  ((ushort4*)yl)[gid] = l;
}

// ---------------- KNN-128 MFMA filter: approx top-3 per row ----------------
__global__ __launch_bounds__(256) void pn_knn_mfma(const unsigned short* __restrict__ Yh,
                                                   const unsigned short* __restrict__ Yl,
                                                   const float* __restrict__ sqn,
                                                   int4* __restrict__ cand) {
  __shared__ __align__(16) unsigned short Ah[128*72];
  __shared__ __align__(16) unsigned short Al[128*72];
  __shared__ __align__(16) unsigned short Bh[128*72];
  __shared__ __align__(16) unsigned short Bl[128*72];
  __shared__ float sqs[1024];
  int t = threadIdx.x;
  int b  = blockIdx.x >> 3;
  int it = blockIdx.x & 7;
  int i0 = it * 128;
  int lane = t & 63, wave = t >> 6;
  int quad = lane >> 4, l16 = lane & 15;
  #pragma unroll
  for (int s = 0; s < 4; ++s) sqs[t + 256*s] = sqn[b*1024 + t + 256*s];

  float D1[8], D2[8], D3[8]; int J1[8], J2[8], J3[8];
  #pragma unroll
  for (int r = 0; r < 8; ++r) {
    D1[r] = FLT_MAX; D2[r] = FLT_MAX; D3[r] = FLT_MAX;
    J1[r] = 0x7fffffff; J2[r] = 0x7fffffff; J3[r] = 0x7fffffff;
  }

  int sr = t >> 1, shf = t & 1;

  #pragma unroll 1
  for (int jc = 0; jc < 8; ++jc) {
    f32x4 acc[2][8];
    #pragma unroll
    for (int s = 0; s < 2; ++s)
      #pragma unroll
      for (int js = 0; js < 8; ++js)
        acc[s][js] = (f32x4){0.f, 0.f, 0.f, 0.f};

    #pragma unroll 1
    for (int kc = 0; kc < 2; ++kc) {
      __syncthreads();
      {
        size_t ga = (size_t)(b*1024 + i0 + sr) * 128 + kc*64 + shf*32;
        size_t gb = (size_t)(b*1024 + jc*128 + sr) * 128 + kc*64 + shf*32;
        const uint4* sAh = (const uint4*)&Yh[ga];
        const uint4* sAl = (const uint4*)&Yl[ga];
        const uint4* sBh = (const uint4*)&Yh[gb];
        const uint4* sBl = (const uint4*)&Yl[gb];
        uint4* dAh = (uint4*)&Ah[sr*72 + shf*32];
        uint4* dAl = (uint4*)&Al[sr*72 + shf*32];
        uint4* dBh = (uint4*)&Bh[sr*72 + shf*32];
        uint4* dBl = (uint4*)&Bl[sr*72 + shf*32];
        #pragma unroll
        for (int q = 0; q < 4; ++q) {
          dAh[q] = sAh[q]; dAl[q] = sAl[q];
          dBh[q] = sBh[q]; dBl[q] = sBl[q];
        }
      }
      __syncthreads();
      #pragma unroll
      for (int ks = 0; ks < 2; ++ks) {
        int ko = ks*32 + quad*8;
        short8 ah0 = *(const short8*)&Ah[(wave*32 + l16)*72 + ko];
        short8 ah1 = *(const short8*)&Ah[(wave*32 + 16 + l16)*72 + ko];
        short8 al0 = *(const short8*)&Al[(wave*32 + l16)*72 + ko];
        short8 al1 = *(const short8*)&Al[(wave*32 + 16 + l16)*72 + ko];
        #pragma unroll
        for (int js = 0; js < 8; ++js) {
          short8 bh = *(const short8*)&Bh[(js*16 + l16)*72 + ko];
          short8 bl = *(const short8*)&Bl[(js*16 + l16)*72 + ko];
          acc[0][js] = __builtin_amdgcn_mfma_f32_16x16x32_bf16(ah0, bh, acc[0][js], 0, 0, 0);
          acc[0][js] = __builtin_amdgcn_mfma_f32_16x16x32_bf16(ah0, bl, acc[0][js], 0, 0, 0);
          acc[0][js] = __builtin_amdgcn_mfma_f32_16x16x32_bf16(al0, bh, acc[0][js], 0, 0, 0);
          acc[0][js] = __builtin_amdgcn_mfma_f32_16x16x32_bf16(al0, bl, acc[0][js], 0, 0, 0);
          acc[1][js] = __builtin_amdgcn_mfma_f32_16x16x32_bf16(ah1, bh, acc[1][js], 0, 0, 0);
          acc[1][js] = __builtin_amdgcn_mfma_f32_16x16x32_bf16(ah1, bl, acc[1][js], 0, 0, 0);
          acc[1][js] = __builtin_amdgcn_mfma_f32_16x16x32_bf16(al1, bh, acc[1][js], 0, 0, 0);
          acc[1][js] = __builtin_amdgcn_mfma_f32_16x16x32_bf16(al1, bl, acc[1][js], 0, 0, 0);
        }
      }
    }
    #pragma unroll
    for (int js = 0; js < 8; ++js) {
      int jg = jc*128 + js*16 + l16;
      float sj = sqs[jg];
      #pragma unroll
      for (int s = 0; s < 2; ++s)
        #pragma unroll
        for (int r = 0; r < 4; ++r) {
          float dd = fmaf(-2.f, acc[s][js][r], sj);
          int id8 = s*4 + r;
          top3_update(D1[id8], J1[id8], D2[id8], J2[id8], D3[id8], J3[id8], dd, jg);
        }
    }
  }

  #pragma unroll
  for (int id8 = 0; id8 < 8; ++id8) {
    #pragma unroll
    for (int m = 1; m < 16; m <<= 1) {
      float o1 = __shfl_xor(D1[id8], m, 64); int p1 = __shfl_xor(J1[id8], m, 64);
      float o2 = __shfl_xor(D2[id8], m, 64); int p2 = __shfl_xor(J2[id8], m, 64);
      float o3 = __shfl_xor(D3[id8], m, 64); int p3 = __shfl_xor(J3[id8], m, 64);
      top3_update(D1[id8], J1[id8], D2[id8], J2[id8], D3[id8], J3[id8], o1, p1);
      top3_update(D1[id8], J1[id8], D2[id8], J2[id8], D3[id8], J3[id8], o2, p2);
      top3_update(D1[id8], J1[id8], D2[id8], J2[id8], D3[id8], J3[id8], o3, p3);
    }
    if (l16 == 0) {
      int s = id8 >> 2, r = id8 & 3;
      int row = b*1024 + i0 + wave*32 + s*16 + quad*4 + r;
      cand[row] = make_int4(J1[id8], J2[id8], J3[id8], 0x7fffffff);
    }
  }
}

// ---------------- exact rescore of 3 candidates (128-dim) ----------------
__global__ __launch_bounds__(256) void pn_knn_rescore(const float* __restrict__ Y,
                                                      const float* __restrict__ sqn,
                                                      const int4* __restrict__ cand,
                                                      int* __restrict__ idx) {
  int gid = blockIdx.x * 256 + threadIdx.x;
  int row = gid >> 2, c = gid & 3;
  int base = (row >> 10) << 10;
  int4 cd = cand[row];
  int cj = (c == 0) ? cd.x : (c == 1) ? cd.y : cd.z;
  const float4* yi = (const float4*)&Y[(size_t)row * 128];
  const float4* yj = (const float4*)&Y[(size_t)(base + cj) * 128];
  float acc = 0.f;
  #pragma unroll 8
  for (int q = 0; q < 32; ++q) {
    float4 a = yi[q], bq = yj[q];
    acc = fmaf(a.x, bq.x, acc);
    acc = fmaf(a.y, bq.y, acc);
    acc = fmaf(a.z, bq.z, acc);
    acc = fmaf(a.w, bq.w, acc);
  }
  float dd = sqn[row] + sqn[base + cj] - 2.0f * acc;
  int jv = cj;
  if (c == 3) { dd = FLT_MAX; jv = 0x7fffffff; }
  float d1 = dd, d2 = FLT_MAX; int j1 = jv, j2 = 0x7fffffff;
  top2_merge_xor(d1, j1, d2, j2, 1);
  top2_merge_xor(d1, j1, d2, j2, 2);
  if (c == 0) {
    idx[row*2+0] = j1;
    idx[row*2+1] = j2;
  }
}

// ---------------- edge epilogue ----------------
__global__ __launch_bounds__(256) void pn_edge_max(const float* __restrict__ U,
                                                   const float* __restrict__ V,
                                                   const int* __restrict__ idx,
                                                   const float* __restrict__ bias,
                                                   float* __restrict__ y) {
  int gid = blockIdx.x * 256 + threadIdx.x;
  int i = gid >> 5, c4 = (gid & 31) << 2;
  int base = (i >> 10) << 10;
  int j0 = idx[i*2+0], j1 = idx[i*2+1];
  float4 u  = *(const float4*)&U[(size_t)i*128 + c4];
  float4 vi = *(const float4*)&V[(size_t)i*128 + c4];
  float4 v0 = *(const float4*)&V[(size_t)(base + j0)*128 + c4];
  float4 v1 = *(const float4*)&V[(size_t)(base + j1)*128 + c4];
  float4 bb = *(const float4*)&bias[c4];
  float4 o;
  o.x = fmaxf(fmaxf(u.x + v0.x - vi.x + bb.x, u.x + v1.x - vi.x + bb.x), 0.f);
  o.y = fmaxf(fmaxf(u.y + v0.y - vi.y + bb.y, u.y + v1.y - vi.y + bb.y), 0.f);
  o.z = fmaxf(fmaxf(u.z + v0.z - vi.z + bb.z, u.z + v1.z - vi.z + bb.z), 0.f);
  o.w = fmaxf(fmaxf(u.w + v0.w - vi.w + bb.w, u.w + v1.w - vi.w + bb.w), 0.f);
  *(float4*)&y[(size_t)i*128 + c4] = o;
}

// ---------------- pooling: 4 n-chunks + combine ----------------
__global__ __launch_bounds__(384) void pn_pool1(const float* __restrict__ y1,
                                                const float* __restrict__ y2,
                                                const float* __restrict__ y3,
                                                float* __restrict__ pp) {
  int b = blockIdx.x >> 2, ch = blockIdx.x & 3, c = threadIdx.x;
  const float* src = (c < 128) ? (y1 + (size_t)b * 131072 + c)
                   : (c < 256) ? (y2 + (size_t)b * 131072 + (c - 128))
                               : (y3 + (size_t)b * 131072 + (c - 256));
  src += (size_t)ch * 256 * 128;
  float s = 0.f, mx = -FLT_MAX;
  for (int n = 0; n < 256; ++n) {
    float v = src[(size_t)n * 128];
    s += v; mx = fmaxf(mx, v);
  }
  pp[(size_t)(b*4 + ch) * 768 + c] = s;
  pp[(size_t)(b*4 + ch) * 768 + 384 + c] = mx;
}

__global__ __launch_bounds__(384) void pn_pool2(const float* __restrict__ pp,
                                                float* __restrict__ g) {
  int b = blockIdx.x, c = threadIdx.x;
  float s = 0.f, mx = -FLT_MAX;
  #pragma unroll
  for (int ch = 0; ch < 4; ++ch) {
    s += pp[(size_t)(b*4 + ch) * 768 + c];
    mx = fmaxf(mx, pp[(size_t)(b*4 + ch) * 768 + 384 + c]);
  }
  g[b*768 + c] = s * (1.0f / 1024.0f);
  g[b*768 + 384 + c] = mx;
}

// ---------------- batchnorm ----------------
__global__ __launch_bounds__(256) void pn_bn(const float* __restrict__ g,
                                             const float* __restrict__ gamma,
                                             const float* __restrict__ beta,
                                             float* __restrict__ out) {
  int c = blockIdx.x * 256 + threadIdx.x;
  float mu = 0.f;
  for (int b = 0; b < 64; ++b) mu += g[b*768 + c];
  mu *= (1.0f / 64.0f);
  float var = 0.f;
  for (int b = 0; b < 64; ++b) { float d = g[b*768 + c] - mu; var += d * d; }
  var *= (1.0f / 64.0f);
  float sc = (1.0f / sqrtf(var + 1e-5f)) * gamma[c];
  float sh = beta[c];
  for (int b = 0; b < 64; ++b) out[b*768 + c] = (g[b*768 + c] - mu) * sc + sh;
}

// ---------------- dense 768->768 (+leaky), 4-acc ILP ----------------
__global__ __launch_bounds__(256) void pn_dense(const float* __restrict__ h,
                                                const float* __restrict__ W,
                                                const float* __restrict__ bias,
                                                float* __restrict__ out) {
  int b = blockIdx.x / 3;
  int c = (blockIdx.x % 3) * 256 + threadIdx.x;
  const float* hb = h + (size_t)b * 768;
  float a0 = bias[c], a1 = 0.f, a2 = 0.f, a3 = 0.f;
  for (int w = 0; w < 768; w += 4) {
    a0 = fmaf(hb[w+0], W[(size_t)(w+0)*768 + c], a0);
    a1 = fmaf(hb[w+1], W[(size_t)(w+1)*768 + c], a1);
    a2 = fmaf(hb[w+2], W[(size_t)(w+2)*768 + c], a2);
    a3 = fmaf(hb[w+3], W[(size_t)(w+3)*768 + c], a3);
  }
  float acc = (a0 + a1) + (a2 + a3);
  acc = acc > 0.f ? acc : 0.01f * acc;
  out[b*768 + c] = acc;
}

// ---------------- final 768->1 ----------------
__global__ __launch_bounds__(256) void pn_out(const float* __restrict__ h,
                                              const float* __restrict__ ow,
                                              const float* __restrict__ ob,
                                              float* __restrict__ out) {
  int wid = blockIdx.x * 4 + (threadIdx.x >> 6);
  int lane = threadIdx.x & 63;
  const float* hb = h + (size_t)wid * 768;
  float s = 0.f;
  #pragma unroll
  for (int q = 0; q < 12; ++q) {
    int w = q * 64 + lane;
    s = fmaf(hb[w], ow[w], s);
  }
  #pragma unroll
  for (int m = 1; m < 64; m <<= 1) s += __shfl_xor(s, m, 64);
  if (lane == 0) out[wid] = s + ob[0];
}

extern "C" void kernel_launch(void* const* d_in, const int* in_sizes, int n_in,
                              void* d_out, int out_size, void* d_ws, size_t ws_size,
                              hipStream_t stream) {
  (void)in_sizes; (void)n_in; (void)out_size; (void)ws_size;
  const float* x     = (const float*)d_in[0];
  const float* p1w1  = (const float*)d_in[1];
  const float* p1b1  = (const float*)d_in[2];
  const float* p1w2  = (const float*)d_in[3];
  const float* p1b2  = (const float*)d_in[4];
  const float* cw    = (const float*)d_in[5];
  const float* cb    = (const float*)d_in[6];
  const float* bng   = (const float*)d_in[7];
  const float* bnb   = (const float*)d_in[8];
  const float* linw  = (const float*)d_in[9];
  const float* linb  = (const float*)d_in[10];
  const float* outw  = (const float*)d_in[11];
  const float* outb  = (const float*)d_in[12];
  float* outp = (float*)d_out;

  float* ws = (float*)d_ws;
  const size_t YSZ = (size_t)65536 * 128;
  float* y1 = ws;
  float* y2 = y1 + YSZ;
  float* y3 = y2 + YSZ;
  float* U  = y3 + YSZ;
  float* V  = U + YSZ;
  float* h1 = U;                         // conv1 scratch, dead after gemm_bias
  unsigned short* yh = (unsigned short*)U;           // 16 MB
  unsigned short* yl = (unsigned short*)U + YSZ;     // second 16 MB of U region
  unsigned short* xh5 = (unsigned short*)U;          // 4 MB (dead before h1)
  unsigned short* xl5 = xh5 + (size_t)65536 * 32;    // 4 MB
  int4* cand = (int4*)V;                 // 1 MB; dead before V write
  float* sq = V + YSZ;
  int*   idxb = (int*)(sq + 65536);
  float* g  = (float*)(idxb + 131072);
  float* ha = g + 49152;
  float* hb = ha + 49152;
  float* pp = hb + 49152;                // pool partials: 256*768 floats

  // --- conv1 ---
  pn_split5<<<256, 256, 0, stream>>>(x, xh5, xl5, sq);
  pn_knn5_mfma<<<512, 256, 0, stream>>>(xh5, xl5, sq, cand);
  pn_knn5_rescore<<<256, 256, 0, stream>>>(x, cand, idxb);
  pn_conv1_l1<<<4096, 256, 0, stream>>>(x, idxb, p1w1, p1b1, h1);
  pn_gemm128_bias<<<1024, 256, 0, stream>>>(h1, p1w2, p1b2, y1);
  // --- conv2 ---
  pn_sqnorm<<<256, 256, 0, stream>>>(y1, sq);
  pn_split<<<8192, 256, 0, stream>>>(y1, yh, yl);
  pn_knn_mfma<<<512, 256, 0, stream>>>(yh, yl, sq, cand);
  pn_knn_rescore<<<1024, 256, 0, stream>>>(y1, sq, cand, idxb);
  pn_gemm128_uv<<<1024, 256, 0, stream>>>(y1, cw, U, V);
  pn_edge_max<<<8192, 256, 0, stream>>>(U, V, idxb, cb, y2);
  // --- conv3 ---
  pn_sqnorm<<<256, 256, 0, stream>>>(y2, sq);
  pn_split<<<8192, 256, 0, stream>>>(y2, yh, yl);
  pn_knn_mfma<<<512, 256, 0, stream>>>(yh, yl, sq, cand);
  pn_knn_rescore<<<1024, 256, 0, stream>>>(y2, sq, cand, idxb);
  pn_gemm128_uv<<<1024, 256, 0, stream>>>(y2, cw + 32768, U, V);
  pn_edge_max<<<8192, 256, 0, stream>>>(U, V, idxb, cb + 128, y3);
  // --- head ---
  pn_pool1<<<256, 384, 0, stream>>>(y1, y2, y3, pp);
  pn_pool2<<<64, 384, 0, stream>>>(pp, g);
  pn_bn<<<3, 256, 0, stream>>>(g, bng, bnb, ha);
  pn_dense<<<192, 256, 0, stream>>>(ha, linw + 0*589824, linb + 0*768, hb);
  pn_dense<<<192, 256, 0, stream>>>(hb, linw + 1*589824, linb + 1*768, ha);
  pn_dense<<<192, 256, 0, stream>>>(ha, linw + 2*589824, linb + 2*768, hb);
  pn_dense<<<192, 256, 0, stream>>>(hb, linw + 3*589824, linb + 3*768, ha);
  pn_dense<<<192, 256, 0, stream>>>(ha, linw + 4*589824, linb + 4*768, hb);
  pn_out<<<16, 256, 0, stream>>>(hb, outw, outb, outp);
}